// Round 12
// baseline (362.876 us; speedup 1.0000x reference)
//
#include <hip/hip_runtime.h>
#include <hip/hip_bf16.h>

#define TPB 256
typedef long long ll;

// B=4, S=2048, D=512, H=8, HD=64, DFF=2048, M=B*S=8192

using short8  = __attribute__((ext_vector_type(8))) short;
using short4v = __attribute__((ext_vector_type(4))) short;
using floatx4 = __attribute__((ext_vector_type(4))) float;

__device__ __forceinline__ unsigned short f2bu(float f) {
    union { float f; unsigned int u; } v; v.f = f;
    unsigned int u = v.u;
    return (unsigned short)((u + 0x7fffu + ((u >> 16) & 1u)) >> 16);  // RNE
}

__device__ __forceinline__ float bu2f(unsigned short us) {
    union { unsigned int u; float f; } v; v.u = ((unsigned int)us) << 16;
    return v.f;
}

// pack two f32 -> one u32 of 2 bf16 (RNE), single HW instruction
__device__ __forceinline__ unsigned int cvtpk(float lo, float hi) {
    unsigned int r;
    asm volatile("v_cvt_pk_bf16_f32 %0, %1, %2" : "=v"(r) : "v"(lo), "v"(hi));
    return r;
}

// 16x16x16 bf16 MFMA (A,B = 4 bf16 / 2 VGPR per lane)
__device__ __forceinline__ floatx4 mfma16(short4v a, short4v b, floatx4 c) {
#if __has_builtin(__builtin_amdgcn_mfma_f32_16x16x16bf16_1k)
    return __builtin_amdgcn_mfma_f32_16x16x16bf16_1k(a, b, c, 0, 0, 0);
#else
    floatx4 d;
    asm volatile("v_mfma_f32_16x16x16_bf16 %0, %1, %2, %3"
                 : "=v"(d) : "v"(a), "v"(b), "v"(c));
    return d;
#endif
}

__device__ __forceinline__ void gload16(const unsigned short* g, unsigned short* l) {
    __builtin_amdgcn_global_load_lds(
        (const __attribute__((address_space(1))) void*)g,
        (__attribute__((address_space(3))) void*)l, 16, 0, 0);
}

// Q pre-scale: 0.125 * log2(e); attention exps then use exp2 directly.
#define QSCALE 0.18033688f

// ---------------------------------------------------------------------------
// GEMM body (m97 + rule-21 LDS XOR swizzle): C = A[M,K] @ BT[N,K]^T
//   EPI: 0 = bf16+bias ; 3 = bf16+bias+relu ; 6 = bf16+bias+bf16 residual ;
//        7 = bf16+bias, cols<512 scaled by QSCALE (Q pre-scale)
// ---------------------------------------------------------------------------
template<int BM, int BN, int EPI>
__device__ __forceinline__ void gemm_body(
    const unsigned short* __restrict__ Ap, const unsigned short* __restrict__ BTp,
    const float* __restrict__ bias, void* __restrict__ Cp,
    const unsigned short* __restrict__ Rb,
    int K, ll lda, ll ldb, ll ldc, int bx, int by,
    unsigned short* Asm, unsigned short* Bsm)
{
    constexpr int BK = 64;
    const int tid  = threadIdx.x;
    const int lane = tid & 63;
    const int wave = tid >> 6;
    const int wm = wave >> 1, wn = wave & 1;
    constexpr int WM = BM / 2, WN = BN / 2, FM = WM / 16, FN = WN / 16;

    const ll brow = (ll)bx * BM;
    const ll bcol = (ll)by * BN;
    const int srow = lane >> 3;
    const int ssw  = (((lane & 7) ^ srow)) << 3;      // inverse-swizzled col
    const int kswz = (lane & 7) << 3;                 // read-side XOR (shorts)

    floatx4 acc[FM][FN] = {};

    for (int k0 = 0; k0 < K; k0 += BK) {
        #pragma unroll
        for (int ii = 0; ii < BM / 32; ++ii) {
            int i = wave + ii * 4;
            gload16(Ap + (brow + i * 8 + srow) * lda + k0 + ssw, Asm + i * 512);
        }
        #pragma unroll
        for (int ii = 0; ii < BN / 32; ++ii) {
            int i = wave + ii * 4;
            gload16(BTp + (bcol + i * 8 + srow) * ldb + k0 + ssw, Bsm + i * 512);
        }
        __syncthreads();

        #pragma unroll
        for (int kk = 0; kk < BK; kk += 32) {
            short8 af[FM], bfr[FN];
            const int kidx = (kk + ((lane >> 4) << 3)) ^ kswz;
            const int ar = wm * WM + (lane & 15);
            const int bc = wn * WN + (lane & 15);
            #pragma unroll
            for (int m = 0; m < FM; m++)
                af[m] = *(const short8*)&Asm[(ar + m * 16) * BK + kidx];
            #pragma unroll
            for (int n = 0; n < FN; n++)
                bfr[n] = *(const short8*)&Bsm[(bc + n * 16) * BK + kidx];
            #pragma unroll
            for (int m = 0; m < FM; m++)
                #pragma unroll
                for (int n = 0; n < FN; n++)
                    acc[m][n] = __builtin_amdgcn_mfma_f32_16x16x32_bf16(af[m], bfr[n], acc[m][n], 0, 0, 0);
        }
        __syncthreads();
    }

    const ll crow0 = brow + wm * WM + ((lane >> 4) << 2);
    const ll ccol0 = bcol + wn * WN + (lane & 15);
    #pragma unroll
    for (int m = 0; m < FM; m++) {
        #pragma unroll
        for (int j = 0; j < 4; j++) {
            ll row = crow0 + m * 16 + j;
            #pragma unroll
            for (int np = 0; np < FN; np += 2) {
                ll col0 = ccol0 + np * 16;
                ll col1 = col0 + 16;
                float v0 = acc[m][np][j]     + bias[col0];
                float v1 = acc[m][np + 1][j] + bias[col1];
                if constexpr (EPI == 3) {
                    v0 = v0 > 0.f ? v0 : 0.f;
                    v1 = v1 > 0.f ? v1 : 0.f;
                } else if constexpr (EPI == 6) {
                    v0 += bu2f(Rb[row * ldc + col0]);
                    v1 += bu2f(Rb[row * ldc + col1]);
                } else if constexpr (EPI == 7) {
                    if (col0 < 512) v0 *= QSCALE;
                    if (col1 < 512) v1 *= QSCALE;
                }
                unsigned int r = cvtpk(v0, v1);
                ((unsigned short*)Cp)[row * ldc + col0] = (unsigned short)r;
                ((unsigned short*)Cp)[row * ldc + col1] = (unsigned short)(r >> 16);
            }
        }
    }
}

// ---------------------------------------------------------------------------
// Standalone GEMM kernel with m157 XCD swizzle (nwg % 8 == 0)
// ---------------------------------------------------------------------------
template<int BM, int BN, int EPI>
__global__ __launch_bounds__(TPB) void gemm_k(
    const unsigned short* __restrict__ Ap, const unsigned short* __restrict__ BTp,
    const float* __restrict__ bias, void* __restrict__ Cp,
    const unsigned short* __restrict__ Rb,
    int K, ll lda, ll ldb, ll ldc)
{
    __shared__ unsigned short sh[BM * 64 + BN * 64];
    int nwg = gridDim.x * gridDim.y;
    int sid = blockIdx.y * gridDim.x + blockIdx.x;
    int cpx = nwg >> 3;
    int w = (sid & 7) * cpx + (sid >> 3);
    int bx = w % gridDim.x, by = w / gridDim.x;
    gemm_body<BM, BN, EPI>(Ap, BTp, bias, Cp, Rb, K, lda, ldb, ldc, bx, by,
                           sh, sh + BM * 64);
}

// ---------------------------------------------------------------------------
// atn-writer body: per (bh, qt): recompute S^T = mfma(K,Q) (Q pre-scaled by
// 0.125*log2e), write atn = exp2(t)*il via per-wave LDS transpose ->
// coalesced 512B-run PLAIN stores (L2-routed; full 128B lines).
// Uses 32KB of sh.
// ---------------------------------------------------------------------------
__device__ __forceinline__ void atnwrite_body(
    const unsigned short* __restrict__ qkv, const float* __restrict__ ilbuf,
    float* __restrict__ atn, int bh, int qt, unsigned short* sh)
{
    unsigned short* Qsm = sh;
    unsigned short* Ksm = sh + 8192;
    float* Pst = (float*)sh;            // reuses Qsm region after qf extraction

    const int tid = threadIdx.x, lane = tid & 63, wave = tid >> 6;
    const int c0 = lane & 15, g = lane >> 4;
    const int b = bh >> 3, h = bh & 7;

    const ll qbase  = ((ll)(b * 2048 + qt * 128)) * 1536 + h * 64;
    const ll kbase0 = ((ll)(b * 2048)) * 1536 + 512 + h * 64;
    const int srow = lane >> 3;
    const int ssw  = (((lane & 7) ^ srow)) << 3;
    const int kswz = (lane & 7) << 3;

    #pragma unroll
    for (int ii = 0; ii < 4; ++ii) {
        int i = wave + ii * 4;
        gload16(qkv + qbase + (ll)(i * 8 + srow) * 1536 + ssw, Qsm + i * 512);
    }
    __syncthreads();
    short8 qf[2][2];
    #pragma unroll
    for (int nq = 0; nq < 2; nq++)
        #pragma unroll
        for (int kk = 0; kk < 2; kk++)
            qf[nq][kk] = *(const short8*)&Qsm[(wave * 32 + nq * 16 + c0) * 64 + ((kk * 32 + g * 8) ^ kswz)];

    float il2[2];
    #pragma unroll
    for (int nq = 0; nq < 2; nq++)
        il2[nq] = ilbuf[(ll)bh * 2048 + qt * 128 + wave * 32 + nq * 16 + c0];

    float* myP = Pst + wave * 1024;     // [8][128] f32, XOR-swizzled float4 units

    for (int kb = 0; kb < 16; ++kb) {
        const ll koff = kbase0 + (ll)kb * 128 * 1536;
        #pragma unroll
        for (int ii = 0; ii < 4; ++ii) {
            int i = wave + ii * 4;
            gload16(qkv + koff + (ll)(i * 8 + srow) * 1536 + ssw, Ksm + i * 512);
        }
        __syncthreads();

        floatx4 sacc[8][2] = {};
        #pragma unroll
        for (int kk = 0; kk < 2; kk++)
            #pragma unroll
            for (int mk = 0; mk < 8; mk++) {
                short8 kf = *(const short8*)&Ksm[(mk * 16 + c0) * 64 + ((kk * 32 + g * 8) ^ kswz)];
                #pragma unroll
                for (int nq = 0; nq < 2; nq++)
                    sacc[mk][nq] = __builtin_amdgcn_mfma_f32_16x16x32_bf16(kf, qf[nq][kk], sacc[mk][nq], 0, 0, 0);
            }

        #pragma unroll
        for (int mk = 0; mk < 8; mk++)
            #pragma unroll
            for (int nq = 0; nq < 2; nq++)
                #pragma unroll
                for (int r = 0; r < 4; r++)
                    sacc[mk][nq][r] = exp2f(sacc[mk][nq][r]) * il2[nq];

        #pragma unroll
        for (int nq = 0; nq < 2; nq++) {
            #pragma unroll
            for (int hf = 0; hf < 2; hf++) {
                if ((c0 >> 3) == hf) {
                    int rho = c0 & 7;
                    #pragma unroll
                    for (int mk = 0; mk < 8; mk++) {
                        int k4 = mk * 4 + g;
                        ((floatx4*)myP)[rho * 32 + (k4 ^ rho)] = sacc[mk][nq];
                    }
                }
                const ll grow = (ll)bh * 2048 + qt * 128 + wave * 32 + nq * 16 + hf * 8;
                #pragma unroll
                for (int t = 0; t < 4; t++) {
                    int rr = t * 2 + (lane >> 5);
                    int k4r = lane & 31;
                    floatx4 v = ((const floatx4*)myP)[rr * 32 + (k4r ^ rr)];
                    *(floatx4*)(atn + (grow + rr) * 2048 + kb * 128 + k4r * 4) = v;
                }
            }
        }
        __syncthreads();
    }
}

// ---------------------------------------------------------------------------
// Attention pass 1 body: per (bh, qt): double-buffered K/V (counted vmcnt(8),
// raw s_barrier), no-max exp2 softmax (pre-scaled Q), x16-MFMA PV.
// Uses 64KB of sh (Kbuf0|Kbuf1|Vbuf0|Vbuf1, 16KB each).
// ---------------------------------------------------------------------------
__device__ __forceinline__ void attn1_body(
    const unsigned short* __restrict__ qkv, const unsigned short* __restrict__ vt,
    unsigned short* __restrict__ attnb, float* __restrict__ ilbuf,
    int bh, int qt, unsigned short* sh)
{
    const int tid = threadIdx.x, lane = tid & 63, wave = tid >> 6;
    const int c0 = lane & 15, g = lane >> 4;
    const int srow = lane >> 3;
    const int ssw  = (((lane & 7) ^ srow)) << 3;
    const int kswz = (lane & 7) << 3;
    const int b = bh >> 3, h = bh & 7;

    const ll qbase  = ((ll)(b * 2048 + qt * 128)) * 1536 + h * 64;
    const ll kbase0 = ((ll)(b * 2048)) * 1536 + 512 + h * 64;
    const unsigned short* vbase = vt + (ll)bh * 64 * 2048;

    // stage Q [128][64] into buf0 (swizzled), pull B-fragments to registers
    #pragma unroll
    for (int ii = 0; ii < 4; ++ii) {
        int i = wave + ii * 4;
        gload16(qkv + qbase + (ll)(i * 8 + srow) * 1536 + ssw, sh + i * 512);
    }
    __syncthreads();
    short8 qf[2][2];
    #pragma unroll
    for (int nq = 0; nq < 2; nq++)
        #pragma unroll
        for (int kk = 0; kk < 2; kk++)
            qf[nq][kk] = *(const short8*)&sh[(wave * 32 + nq * 16 + c0) * 64 + ((kk * 32 + g * 8) ^ kswz)];
    __syncthreads();

    floatx4 oaccT[4][2] = {};
    float l_run[2] = {0.f, 0.f};

#define STAGE_KV(kbx, bb) do {                                                   \
    const ll koff_ = kbase0 + (ll)(kbx) * 128 * 1536;                            \
    unsigned short* Kd_ = sh + ((bb) << 13);                                     \
    unsigned short* Vd_ = sh + 16384 + ((bb) << 13);                             \
    _Pragma("unroll")                                                            \
    for (int ii = 0; ii < 4; ++ii) { int i = wave + ii * 4;                      \
        gload16(qkv + koff_ + (ll)(i * 8 + srow) * 1536 + ssw, Kd_ + i * 512); } \
    _Pragma("unroll")                                                            \
    for (int ii = 0; ii < 4; ++ii) { int i = wave + ii * 4; int s = i * 8 + srow;\
        int vrow = s >> 1; int vslot = ((s & 1) << 3) | (lane & 7);              \
        gload16(vbase + (ll)vrow * 2048 + (kbx) * 128 + ((vslot ^ (vrow & 7)) << 3), \
                Vd_ + i * 512); }                                                \
} while (0)

    STAGE_KV(0, 0);
    for (int kb = 0; kb < 16; ++kb) {
        const int cur = kb & 1;
        if (kb < 15) {
            STAGE_KV(kb + 1, cur ^ 1);
            asm volatile("s_waitcnt vmcnt(8)" ::: "memory");
        } else {
            asm volatile("s_waitcnt vmcnt(0)" ::: "memory");
        }
        __builtin_amdgcn_sched_barrier(0);
        __builtin_amdgcn_s_barrier();
        __builtin_amdgcn_sched_barrier(0);

        unsigned short* Kc = sh + (cur << 13);
        unsigned short* Vc = sh + 16384 + (cur << 13);

        // S^T = mfma(K, Q); Q pre-scaled so sacc is s*0.125*log2e
        floatx4 sacc[8][2] = {};
        #pragma unroll
        for (int kk = 0; kk < 2; kk++)
            #pragma unroll
            for (int mk = 0; mk < 8; mk++) {
                short8 kf = *(const short8*)&Kc[(mk * 16 + c0) * 64 + ((kk * 32 + g * 8) ^ kswz)];
                #pragma unroll
                for (int nq = 0; nq < 2; nq++)
                    sacc[mk][nq] = __builtin_amdgcn_mfma_f32_16x16x32_bf16(kf, qf[nq][kk], sacc[mk][nq], 0, 0, 0);
            }

        // p = exp2(t); l += row-sum
        #pragma unroll
        for (int nq = 0; nq < 2; nq++) {
            float rs = 0.f;
            #pragma unroll
            for (int mk = 0; mk < 8; mk++)
                #pragma unroll
                for (int r = 0; r < 4; r++) {
                    float p = exp2f(sacc[mk][nq][r]);
                    sacc[mk][nq][r] = p;
                    rs += p;
                }
            rs += __shfl_xor(rs, 16);
            rs += __shfl_xor(rs, 32);
            l_run[nq] += rs;
        }

        // PV via x16 MFMA: P is already in B-fragment layout (k = g*4+r)
        #pragma unroll
        for (int mk = 0; mk < 8; mk++) {
            short4v pb[2];
            #pragma unroll
            for (int nq = 0; nq < 2; nq++) {
                union { unsigned int u[2]; short4v s; } pu;
                pu.u[0] = cvtpk(sacc[mk][nq][0], sacc[mk][nq][1]);
                pu.u[1] = cvtpk(sacc[mk][nq][2], sacc[mk][nq][3]);
                pb[nq] = pu.s;
            }
            #pragma unroll
            for (int mk2 = 0; mk2 < 4; mk2++) {
                short4v vf = *(const short4v*)&Vc[(mk2 * 16 + c0) * 128 + ((mk * 16 + g * 4) ^ kswz)];
                #pragma unroll
                for (int nq = 0; nq < 2; nq++)
                    oaccT[mk2][nq] = mfma16(vf, pb[nq], oaccT[mk2][nq]);
            }
        }
        __builtin_amdgcn_sched_barrier(0);
        __builtin_amdgcn_s_barrier();
        __builtin_amdgcn_sched_barrier(0);
    }
#undef STAGE_KV

    const float il[2] = { 1.0f / l_run[0], 1.0f / l_run[1] };

    #pragma unroll
    for (int nq = 0; nq < 2; nq++) {
        int qrow = qt * 128 + wave * 32 + nq * 16 + c0;
        ll row = (ll)b * 2048 + qrow;
        #pragma unroll
        for (int mk2 = 0; mk2 < 4; mk2++) {
            int col = h * 64 + mk2 * 16 + g * 4;
            unsigned int r0 = cvtpk(oaccT[mk2][nq][0] * il[nq], oaccT[mk2][nq][1] * il[nq]);
            unsigned int r1 = cvtpk(oaccT[mk2][nq][2] * il[nq], oaccT[mk2][nq][3] * il[nq]);
            int2 tb = { (int)r0, (int)r1 };
            *(int2*)&attnb[row * 512 + col] = tb;
        }
        if (g == 0) ilbuf[(ll)bh * 2048 + qrow] = il[nq];
    }
}

// ---------------------------------------------------------------------------
// Attention half A: bh 0..15 (256 blocks, XCD-pinned: xcd owns 2 bh)
// ---------------------------------------------------------------------------
__global__ __launch_bounds__(TPB) void attn1a_k(
    const unsigned short* __restrict__ qkv, const unsigned short* __restrict__ vt,
    unsigned short* __restrict__ attnb, float* __restrict__ ilbuf)
{
    __shared__ unsigned short sh[32768];
    const int n = blockIdx.x;
    const int bh = (n & 7) * 2 + ((n >> 3) & 1);
    const int qt = n >> 4;
    attn1_body(qkv, vt, attnb, ilbuf, bh, qt, sh);
}

// ---------------------------------------------------------------------------
// Fused 1: writers bh 0..7 (128 blocks, first) || attention half B bh 16..31
// ---------------------------------------------------------------------------
__global__ __launch_bounds__(TPB) void fused1_k(
    const unsigned short* __restrict__ qkv, const unsigned short* __restrict__ vt,
    unsigned short* __restrict__ attnb, float* __restrict__ ilbuf,
    float* __restrict__ atn)
{
    __shared__ unsigned short sh[32768];
    const int bid = blockIdx.x;
    if (bid < 128) {
        atnwrite_body(qkv, ilbuf, atn, bid & 7, bid >> 3, sh);
    } else {
        const int m = bid - 128;
        const int bh = 16 + (m & 7) * 2 + ((m >> 3) & 1);
        const int qt = m >> 4;
        attn1_body(qkv, vt, attnb, ilbuf, bh, qt, sh);
    }
}

// ---------------------------------------------------------------------------
// Fused GEMM+writers: writer blocks [0, WRCNT*16) for bh WRBH0..WRBH0+WRCNT-1,
// then GX*GY GEMM blocks (XCD-swizzled).
// ---------------------------------------------------------------------------
template<int WRBH0, int WRCNT, int GX, int GY, int BM, int BN, int EPI>
__global__ __launch_bounds__(TPB) void fusedg_k(
    const unsigned short* __restrict__ qkv, const float* __restrict__ ilbuf,
    float* __restrict__ atn,
    const unsigned short* __restrict__ Ap, const unsigned short* __restrict__ BTp,
    const float* __restrict__ bias, void* __restrict__ Cp,
    const unsigned short* __restrict__ Rb,
    int K, ll lda, ll ldb, ll ldc)
{
    __shared__ unsigned short sh[16384];
    const int bid = blockIdx.x;
    constexpr int WRN = WRCNT * 16;
    if (bid < WRN) {
        atnwrite_body(qkv, ilbuf, atn, WRBH0 + bid % WRCNT, bid / WRCNT, sh);
    } else {
        int sid = bid - WRN;
        constexpr int NWG = GX * GY;
        int w = (sid & 7) * (NWG >> 3) + (sid >> 3);
        int bx = w % GX, by = w / GX;
        gemm_body<BM, BN, EPI>(Ap, BTp, bias, Cp, Rb, K, lda, ldb, ldc, bx, by,
                               sh, sh + BM * 64);
    }
}

// ---------------------------------------------------------------------------
// LayerNorm over rows of 512 bf16 -> f32 out (wave per row, 4 rows/block)
// ---------------------------------------------------------------------------
__global__ __launch_bounds__(TPB) void ln_k(const unsigned short* __restrict__ y,
                                            const float* __restrict__ gamma,
                                            const float* __restrict__ beta,
                                            float* __restrict__ out)
{
    const int lane = threadIdx.x & 63;
    const ll row = (ll)blockIdx.x * 4 + (threadIdx.x >> 6);
    short8 v = *(const short8*)(y + row * 512 + lane * 8);
    float f[8];
    float s = 0.f, q = 0.f;
    #pragma unroll
    for (int j = 0; j < 8; j++) {
        f[j] = bu2f((unsigned short)v[j]);
        s += f[j]; q += f[j] * f[j];
    }
    #pragma unroll
    for (int off = 32; off; off >>= 1) { s += __shfl_xor(s, off); q += __shfl_xor(q, off); }
    const float mu  = s * (1.0f / 512.0f);
    const float var = q * (1.0f / 512.0f) - mu * mu;
    const float rs  = rsqrtf(var + 1e-5f);

    float4 g0 = *(const float4*)(gamma + lane * 8);
    float4 g1 = *(const float4*)(gamma + lane * 8 + 4);
    float4 e0 = *(const float4*)(beta  + lane * 8);
    float4 e1 = *(const float4*)(beta  + lane * 8 + 4);
    floatx4 o0, o1;
    o0[0] = (f[0] - mu) * rs * g0.x + e0.x;  o0[1] = (f[1] - mu) * rs * g0.y + e0.y;
    o0[2] = (f[2] - mu) * rs * g0.z + e0.z;  o0[3] = (f[3] - mu) * rs * g0.w + e0.w;
    o1[0] = (f[4] - mu) * rs * g1.x + e1.x;  o1[1] = (f[5] - mu) * rs * g1.y + e1.y;
    o1[2] = (f[6] - mu) * rs * g1.z + e1.z;  o1[3] = (f[7] - mu) * rs * g1.w + e1.w;
    *(floatx4*)(out + row * 512 + lane * 8) = o0;
    *(floatx4*)(out + row * 512 + lane * 8 + 4) = o1;
}

// ---------------------------------------------------------------------------
// Prep: weight transposes (32x32 tiles) + bias concat + x cast, block-ranged.
// ---------------------------------------------------------------------------
__global__ __launch_bounds__(TPB) void prep_k(
    const float* __restrict__ Wq, const float* __restrict__ Wk,
    const float* __restrict__ Wv, const float* __restrict__ W1,
    const float* __restrict__ W2,
    const float* __restrict__ bq, const float* __restrict__ bk,
    const float* __restrict__ bv, const float* __restrict__ x,
    unsigned short* __restrict__ wtqkv, unsigned short* __restrict__ wt1,
    unsigned short* __restrict__ wt2, float* __restrict__ bqkv,
    unsigned short* __restrict__ xb)
{
    __shared__ float t[32 * 33];
    const int bid = blockIdx.x;
    const float* W; unsigned short* WT; int K, N, tile;
    if (bid < 256)       { W = Wq; WT = wtqkv;             K = 512;  N = 512;  tile = bid; }
    else if (bid < 512)  { W = Wk; WT = wtqkv + 512 * 512; K = 512;  N = 512;  tile = bid - 256; }
    else if (bid < 768)  { W = Wv; WT = wtqkv + 1024 * 512;K = 512;  N = 512;  tile = bid - 512; }
    else if (bid < 1792) { W = W1; WT = wt1;               K = 512;  N = 2048; tile = bid - 768; }
    else if (bid < 2816) { W = W2; WT = wt2;               K = 2048; N = 512;  tile = bid - 1792; }
    else if (bid < 2822) {
        int i = (bid - 2816) * TPB + threadIdx.x;
        if (i < 512)       bqkv[i] = bq[i];
        else if (i < 1024) bqkv[i] = bk[i - 512];
        else if (i < 1536) bqkv[i] = bv[i - 1024];
        return;
    } else {
        ll i = ((ll)(bid - 2822) * TPB + threadIdx.x) * 4;
        float4 v = *(const float4*)(x + i);
        unsigned int r0 = cvtpk(v.x, v.y), r1 = cvtpk(v.z, v.w);
        int2 tt = { (int)r0, (int)r1 };
        *(int2*)(xb + i) = tt;
        return;
    }
    const int nx = N >> 5;
    const int n0 = (tile % nx) * 32, k0 = (tile / nx) * 32;
    const int tx = threadIdx.x & 31, ty = threadIdx.x >> 5;
    #pragma unroll
    for (int i = ty; i < 32; i += 8) t[i * 33 + tx] = W[(ll)(k0 + i) * N + n0 + tx];
    __syncthreads();
    #pragma unroll
    for (int i = ty; i < 32; i += 8) WT[(ll)(n0 + i) * K + k0 + tx] = f2bu(t[tx * 33 + i]);
}

// ---------------------------------------------------------------------------
// V transpose: vt[(b*H+h)*64 + hd][s] = qkv[b*S+s][1024 + h*64 + hd]
// ---------------------------------------------------------------------------
__global__ __launch_bounds__(TPB) void transv_k(const unsigned short* __restrict__ qkv,
                                                unsigned short* __restrict__ vt)
{
    const int z = blockIdx.y;  const int b = z >> 3, h = z & 7;
    const int s0 = blockIdx.x * 64;
    __shared__ unsigned short t[64][72];
    const unsigned short* src = qkv + ((ll)(b * 2048 + s0)) * 1536 + 1024 + h * 64;
    for (int c = threadIdx.x; c < 512; c += TPB) {
        int r = c >> 3, c8 = (c & 7) << 3;
        *(int4*)&t[r][c8] = *(const int4*)(src + (ll)r * 1536 + c8);
    }
    __syncthreads();
    unsigned short* dst = vt + (ll)z * 64 * 2048 + s0;
    for (int c = threadIdx.x; c < 512; c += TPB) {
        int hd = c >> 3, s8 = (c & 7) << 3;
        unsigned short tmp[8];
        #pragma unroll
        for (int j = 0; j < 8; j++) tmp[j] = t[s8 + j][hd];
        *(int4*)(dst + (ll)hd * 2048 + s8) = *(const int4*)tmp;
    }
}

// ---------------------------------------------------------------------------
extern "C" void kernel_launch(void* const* d_in, const int* in_sizes, int n_in,
                              void* d_out, int out_size, void* d_ws, size_t ws_size,
                              hipStream_t stream)
{
    (void)in_sizes; (void)n_in; (void)out_size; (void)ws_size;
    const float* x     = (const float*)d_in[0];
    const float* Wq    = (const float*)d_in[1];
    const float* bq    = (const float*)d_in[2];
    const float* Wk    = (const float*)d_in[3];
    const float* bk    = (const float*)d_in[4];
    const float* Wv    = (const float*)d_in[5];
    const float* bv    = (const float*)d_in[6];
    const float* W1    = (const float*)d_in[7];
    const float* b1    = (const float*)d_in[8];
    const float* W2    = (const float*)d_in[9];
    const float* b2    = (const float*)d_in[10];
    const float* gamma = (const float*)d_in[11];
    const float* beta  = (const float*)d_in[12];

    char* ws = (char*)d_ws;
    size_t off = 0;
    auto alloc = [&](size_t bytes) -> char* {
        char* p = ws + off; off += (bytes + 255) & ~(size_t)255; return p;
    };
    unsigned short* xb    = (unsigned short*)alloc(8192ll * 512 * 2);
    unsigned short* wtqkv = (unsigned short*)alloc(1536ll * 512 * 2);
    unsigned short* wt1   = (unsigned short*)alloc(2048ll * 512 * 2);
    unsigned short* wt2   = (unsigned short*)alloc(512ll * 2048 * 2);
    float*          bqkv  = (float*)alloc(1536 * 4);
    unsigned short* qkv   = (unsigned short*)alloc(8192ll * 1536 * 2);
    unsigned short* vt    = (unsigned short*)alloc(32ll * 64 * 2048 * 2);
    unsigned short* attnb = (unsigned short*)alloc(8192ll * 512 * 2);
    unsigned short* hmid  = (unsigned short*)alloc(8192ll * 2048 * 2);
    unsigned short* ybuf  = (unsigned short*)alloc(8192ll * 512 * 2);
    float*          ilbuf = (float*)alloc(32ll * 2048 * 4);

    float* outp = (float*)d_out;
    float* atn  = outp + 4194304;     // [B,H,S,S] region

    prep_k<<<2822 + 4096, TPB, 0, stream>>>(Wq, Wk, Wv, W1, W2, bq, bk, bv, x,
                                            wtqkv, wt1, wt2, bqkv, xb);

    // QKV: [8192,512] @ [512,1536] -> qkv bf16; Q columns pre-scaled by QSCALE
    gemm_k<128, 128, 7><<<dim3(64, 12, 1), TPB, 0, stream>>>(
        xb, wtqkv, bqkv, qkv, nullptr, 512, 512, 512, 1536);

    transv_k<<<dim3(32, 32), TPB, 0, stream>>>(qkv, vt);

    // Attention half A: bh 0..15 -> attnb + ilbuf
    attn1a_k<<<256, TPB, 0, stream>>>(qkv, vt, attnb, ilbuf);

    // Fused 1: writers bh 0..7 || attention half B (bh 16..31)
    fused1_k<<<384, TPB, 0, stream>>>(qkv, vt, attnb, ilbuf, atn);

    // Fused 2: writers bh 8..19 || FFN1 relu(attn_out@W1+b1) -> hmid
    fusedg_k<8, 12, 64, 16, 128, 128, 3><<<192 + 1024, TPB, 0, stream>>>(
        qkv, ilbuf, atn,
        attnb, wt1, b1, hmid, nullptr, 512, 512, 512, 2048);

    // Fused 3: writers bh 20..31 || FFN2 hmid@W2+b2+attn_out(bf16) -> ybuf bf16
    fusedg_k<20, 12, 128, 4, 64, 128, 6><<<192 + 512, TPB, 0, stream>>>(
        qkv, ilbuf, atn,
        hmid, wt2, b2, ybuf, attnb, 2048, 2048, 2048, 512);

    ln_k<<<2048, TPB, 0, stream>>>(ybuf, gamma, beta, outp);
}

// Round 13
// 299.228 us; speedup vs baseline: 1.2127x; 1.2127x over previous
//
#include <hip/hip_runtime.h>
#include <hip/hip_bf16.h>

#define TPB 256
typedef long long ll;

// B=4, S=2048, D=512, H=8, HD=64, DFF=2048, M=B*S=8192

using short8  = __attribute__((ext_vector_type(8))) short;
using short4v = __attribute__((ext_vector_type(4))) short;
using floatx4 = __attribute__((ext_vector_type(4))) float;

__device__ __forceinline__ unsigned short f2bu(float f) {
    union { float f; unsigned int u; } v; v.f = f;
    unsigned int u = v.u;
    return (unsigned short)((u + 0x7fffu + ((u >> 16) & 1u)) >> 16);  // RNE
}

__device__ __forceinline__ float bu2f(unsigned short us) {
    union { unsigned int u; float f; } v; v.u = ((unsigned int)us) << 16;
    return v.f;
}

// pack two f32 -> one u32 of 2 bf16 (RNE), single HW instruction
__device__ __forceinline__ unsigned int cvtpk(float lo, float hi) {
    unsigned int r;
    asm volatile("v_cvt_pk_bf16_f32 %0, %1, %2" : "=v"(r) : "v"(lo), "v"(hi));
    return r;
}

// 16x16x16 bf16 MFMA (A,B = 4 bf16 / 2 VGPR per lane)
__device__ __forceinline__ floatx4 mfma16(short4v a, short4v b, floatx4 c) {
#if __has_builtin(__builtin_amdgcn_mfma_f32_16x16x16bf16_1k)
    return __builtin_amdgcn_mfma_f32_16x16x16bf16_1k(a, b, c, 0, 0, 0);
#else
    floatx4 d;
    asm volatile("v_mfma_f32_16x16x16_bf16 %0, %1, %2, %3"
                 : "=v"(d) : "v"(a), "v"(b), "v"(c));
    return d;
#endif
}

__device__ __forceinline__ void gload16(const unsigned short* g, unsigned short* l) {
    __builtin_amdgcn_global_load_lds(
        (const __attribute__((address_space(1))) void*)g,
        (__attribute__((address_space(3))) void*)l, 16, 0, 0);
}

// Q pre-scale: 0.125 * log2(e); attention exps then use exp2 directly.
#define QSCALE 0.18033688f

// ---------------------------------------------------------------------------
// GEMM body (m97 + rule-21 LDS XOR swizzle): C = A[M,K] @ BT[N,K]^T
//   EPI: 0 = bf16+bias ; 3 = bf16+bias+relu ; 6 = bf16+bias+bf16 residual ;
//        7 = bf16+bias, cols<512 scaled by QSCALE (Q pre-scale)
// ---------------------------------------------------------------------------
template<int BM, int BN, int EPI>
__device__ __forceinline__ void gemm_body(
    const unsigned short* __restrict__ Ap, const unsigned short* __restrict__ BTp,
    const float* __restrict__ bias, void* __restrict__ Cp,
    const unsigned short* __restrict__ Rb,
    int K, ll lda, ll ldb, ll ldc, int bx, int by,
    unsigned short* Asm, unsigned short* Bsm)
{
    constexpr int BK = 64;
    const int tid  = threadIdx.x;
    const int lane = tid & 63;
    const int wave = tid >> 6;
    const int wm = wave >> 1, wn = wave & 1;
    constexpr int WM = BM / 2, WN = BN / 2, FM = WM / 16, FN = WN / 16;

    const ll brow = (ll)bx * BM;
    const ll bcol = (ll)by * BN;
    const int srow = lane >> 3;
    const int ssw  = (((lane & 7) ^ srow)) << 3;      // inverse-swizzled col
    const int kswz = (lane & 7) << 3;                 // read-side XOR (shorts)

    floatx4 acc[FM][FN] = {};

    for (int k0 = 0; k0 < K; k0 += BK) {
        #pragma unroll
        for (int ii = 0; ii < BM / 32; ++ii) {
            int i = wave + ii * 4;
            gload16(Ap + (brow + i * 8 + srow) * lda + k0 + ssw, Asm + i * 512);
        }
        #pragma unroll
        for (int ii = 0; ii < BN / 32; ++ii) {
            int i = wave + ii * 4;
            gload16(BTp + (bcol + i * 8 + srow) * ldb + k0 + ssw, Bsm + i * 512);
        }
        __syncthreads();

        #pragma unroll
        for (int kk = 0; kk < BK; kk += 32) {
            short8 af[FM], bfr[FN];
            const int kidx = (kk + ((lane >> 4) << 3)) ^ kswz;
            const int ar = wm * WM + (lane & 15);
            const int bc = wn * WN + (lane & 15);
            #pragma unroll
            for (int m = 0; m < FM; m++)
                af[m] = *(const short8*)&Asm[(ar + m * 16) * BK + kidx];
            #pragma unroll
            for (int n = 0; n < FN; n++)
                bfr[n] = *(const short8*)&Bsm[(bc + n * 16) * BK + kidx];
            #pragma unroll
            for (int m = 0; m < FM; m++)
                #pragma unroll
                for (int n = 0; n < FN; n++)
                    acc[m][n] = __builtin_amdgcn_mfma_f32_16x16x32_bf16(af[m], bfr[n], acc[m][n], 0, 0, 0);
        }
        __syncthreads();
    }

    const ll crow0 = brow + wm * WM + ((lane >> 4) << 2);
    const ll ccol0 = bcol + wn * WN + (lane & 15);
    #pragma unroll
    for (int m = 0; m < FM; m++) {
        #pragma unroll
        for (int j = 0; j < 4; j++) {
            ll row = crow0 + m * 16 + j;
            #pragma unroll
            for (int np = 0; np < FN; np += 2) {
                ll col0 = ccol0 + np * 16;
                ll col1 = col0 + 16;
                float v0 = acc[m][np][j]     + bias[col0];
                float v1 = acc[m][np + 1][j] + bias[col1];
                if constexpr (EPI == 3) {
                    v0 = v0 > 0.f ? v0 : 0.f;
                    v1 = v1 > 0.f ? v1 : 0.f;
                } else if constexpr (EPI == 6) {
                    v0 += bu2f(Rb[row * ldc + col0]);
                    v1 += bu2f(Rb[row * ldc + col1]);
                } else if constexpr (EPI == 7) {
                    if (col0 < 512) v0 *= QSCALE;
                    if (col1 < 512) v1 *= QSCALE;
                }
                unsigned int r = cvtpk(v0, v1);
                ((unsigned short*)Cp)[row * ldc + col0] = (unsigned short)r;
                ((unsigned short*)Cp)[row * ldc + col1] = (unsigned short)(r >> 16);
            }
        }
    }
}

// ---------------------------------------------------------------------------
// Standalone GEMM kernel with m157 XCD swizzle (nwg % 8 == 0)
// ---------------------------------------------------------------------------
template<int BM, int BN, int EPI>
__global__ __launch_bounds__(TPB) void gemm_k(
    const unsigned short* __restrict__ Ap, const unsigned short* __restrict__ BTp,
    const float* __restrict__ bias, void* __restrict__ Cp,
    const unsigned short* __restrict__ Rb,
    int K, ll lda, ll ldb, ll ldc)
{
    __shared__ unsigned short sh[BM * 64 + BN * 64];
    int nwg = gridDim.x * gridDim.y;
    int sid = blockIdx.y * gridDim.x + blockIdx.x;
    int cpx = nwg >> 3;
    int w = (sid & 7) * cpx + (sid >> 3);
    int bx = w % gridDim.x, by = w / gridDim.x;
    gemm_body<BM, BN, EPI>(Ap, BTp, bias, Cp, Rb, K, lda, ldb, ldc, bx, by,
                           sh, sh + BM * 64);
}

// ---------------------------------------------------------------------------
// atn-writer body: per (bh, qt): recompute S^T = mfma(K,Q) (Q pre-scaled by
// 0.125*log2e), write atn = exp2(t)*il via per-wave LDS transpose ->
// coalesced 512B-run NONTEMPORAL stores (L2-bypass; full 128B lines).
// Uses 32KB of sh.
// ---------------------------------------------------------------------------
__device__ __forceinline__ void atnwrite_body(
    const unsigned short* __restrict__ qkv, const float* __restrict__ ilbuf,
    float* __restrict__ atn, int bh, int qt, unsigned short* sh)
{
    unsigned short* Qsm = sh;
    unsigned short* Ksm = sh + 8192;
    float* Pst = (float*)sh;            // reuses Qsm region after qf extraction

    const int tid = threadIdx.x, lane = tid & 63, wave = tid >> 6;
    const int c0 = lane & 15, g = lane >> 4;
    const int b = bh >> 3, h = bh & 7;

    const ll qbase  = ((ll)(b * 2048 + qt * 128)) * 1536 + h * 64;
    const ll kbase0 = ((ll)(b * 2048)) * 1536 + 512 + h * 64;
    const int srow = lane >> 3;
    const int ssw  = (((lane & 7) ^ srow)) << 3;
    const int kswz = (lane & 7) << 3;

    #pragma unroll
    for (int ii = 0; ii < 4; ++ii) {
        int i = wave + ii * 4;
        gload16(qkv + qbase + (ll)(i * 8 + srow) * 1536 + ssw, Qsm + i * 512);
    }
    __syncthreads();
    short8 qf[2][2];
    #pragma unroll
    for (int nq = 0; nq < 2; nq++)
        #pragma unroll
        for (int kk = 0; kk < 2; kk++)
            qf[nq][kk] = *(const short8*)&Qsm[(wave * 32 + nq * 16 + c0) * 64 + ((kk * 32 + g * 8) ^ kswz)];

    float il2[2];
    #pragma unroll
    for (int nq = 0; nq < 2; nq++)
        il2[nq] = ilbuf[(ll)bh * 2048 + qt * 128 + wave * 32 + nq * 16 + c0];

    float* myP = Pst + wave * 1024;     // [8][128] f32, XOR-swizzled float4 units

    for (int kb = 0; kb < 16; ++kb) {
        const ll koff = kbase0 + (ll)kb * 128 * 1536;
        #pragma unroll
        for (int ii = 0; ii < 4; ++ii) {
            int i = wave + ii * 4;
            gload16(qkv + koff + (ll)(i * 8 + srow) * 1536 + ssw, Ksm + i * 512);
        }
        __syncthreads();

        floatx4 sacc[8][2] = {};
        #pragma unroll
        for (int kk = 0; kk < 2; kk++)
            #pragma unroll
            for (int mk = 0; mk < 8; mk++) {
                short8 kf = *(const short8*)&Ksm[(mk * 16 + c0) * 64 + ((kk * 32 + g * 8) ^ kswz)];
                #pragma unroll
                for (int nq = 0; nq < 2; nq++)
                    sacc[mk][nq] = __builtin_amdgcn_mfma_f32_16x16x32_bf16(kf, qf[nq][kk], sacc[mk][nq], 0, 0, 0);
            }

        #pragma unroll
        for (int mk = 0; mk < 8; mk++)
            #pragma unroll
            for (int nq = 0; nq < 2; nq++)
                #pragma unroll
                for (int r = 0; r < 4; r++)
                    sacc[mk][nq][r] = exp2f(sacc[mk][nq][r]) * il2[nq];

        #pragma unroll
        for (int nq = 0; nq < 2; nq++) {
            #pragma unroll
            for (int hf = 0; hf < 2; hf++) {
                if ((c0 >> 3) == hf) {
                    int rho = c0 & 7;
                    #pragma unroll
                    for (int mk = 0; mk < 8; mk++) {
                        int k4 = mk * 4 + g;
                        ((floatx4*)myP)[rho * 32 + (k4 ^ rho)] = sacc[mk][nq];
                    }
                }
                const ll grow = (ll)bh * 2048 + qt * 128 + wave * 32 + nq * 16 + hf * 8;
                #pragma unroll
                for (int t = 0; t < 4; t++) {
                    int rr = t * 2 + (lane >> 5);
                    int k4r = lane & 31;
                    floatx4 v = ((const floatx4*)myP)[rr * 32 + (k4r ^ rr)];
                    __builtin_nontemporal_store(
                        v, (floatx4*)(atn + (grow + rr) * 2048 + kb * 128 + k4r * 4));
                }
            }
        }
        __syncthreads();
    }
}

// ---------------------------------------------------------------------------
// Attention pass 1 body: per (bh, qt): double-buffered K/V (counted vmcnt(8),
// raw s_barrier), no-max exp2 softmax (pre-scaled Q), x16-MFMA PV.
// Uses 64KB of sh (Kbuf0|Kbuf1|Vbuf0|Vbuf1, 16KB each).
// ---------------------------------------------------------------------------
__device__ __forceinline__ void attn1_body(
    const unsigned short* __restrict__ qkv, const unsigned short* __restrict__ vt,
    unsigned short* __restrict__ attnb, float* __restrict__ ilbuf,
    int bh, int qt, unsigned short* sh)
{
    const int tid = threadIdx.x, lane = tid & 63, wave = tid >> 6;
    const int c0 = lane & 15, g = lane >> 4;
    const int srow = lane >> 3;
    const int ssw  = (((lane & 7) ^ srow)) << 3;
    const int kswz = (lane & 7) << 3;
    const int b = bh >> 3, h = bh & 7;

    const ll qbase  = ((ll)(b * 2048 + qt * 128)) * 1536 + h * 64;
    const ll kbase0 = ((ll)(b * 2048)) * 1536 + 512 + h * 64;
    const unsigned short* vbase = vt + (ll)bh * 64 * 2048;

    // stage Q [128][64] into buf0 (swizzled), pull B-fragments to registers
    #pragma unroll
    for (int ii = 0; ii < 4; ++ii) {
        int i = wave + ii * 4;
        gload16(qkv + qbase + (ll)(i * 8 + srow) * 1536 + ssw, sh + i * 512);
    }
    __syncthreads();
    short8 qf[2][2];
    #pragma unroll
    for (int nq = 0; nq < 2; nq++)
        #pragma unroll
        for (int kk = 0; kk < 2; kk++)
            qf[nq][kk] = *(const short8*)&sh[(wave * 32 + nq * 16 + c0) * 64 + ((kk * 32 + g * 8) ^ kswz)];
    __syncthreads();

    floatx4 oaccT[4][2] = {};
    float l_run[2] = {0.f, 0.f};

#define STAGE_KV(kbx, bb) do {                                                   \
    const ll koff_ = kbase0 + (ll)(kbx) * 128 * 1536;                            \
    unsigned short* Kd_ = sh + ((bb) << 13);                                     \
    unsigned short* Vd_ = sh + 16384 + ((bb) << 13);                             \
    _Pragma("unroll")                                                            \
    for (int ii = 0; ii < 4; ++ii) { int i = wave + ii * 4;                      \
        gload16(qkv + koff_ + (ll)(i * 8 + srow) * 1536 + ssw, Kd_ + i * 512); } \
    _Pragma("unroll")                                                            \
    for (int ii = 0; ii < 4; ++ii) { int i = wave + ii * 4; int s = i * 8 + srow;\
        int vrow = s >> 1; int vslot = ((s & 1) << 3) | (lane & 7);              \
        gload16(vbase + (ll)vrow * 2048 + (kbx) * 128 + ((vslot ^ (vrow & 7)) << 3), \
                Vd_ + i * 512); }                                                \
} while (0)

    STAGE_KV(0, 0);
    for (int kb = 0; kb < 16; ++kb) {
        const int cur = kb & 1;
        if (kb < 15) {
            STAGE_KV(kb + 1, cur ^ 1);
            asm volatile("s_waitcnt vmcnt(8)" ::: "memory");
        } else {
            asm volatile("s_waitcnt vmcnt(0)" ::: "memory");
        }
        __builtin_amdgcn_sched_barrier(0);
        __builtin_amdgcn_s_barrier();
        __builtin_amdgcn_sched_barrier(0);

        unsigned short* Kc = sh + (cur << 13);
        unsigned short* Vc = sh + 16384 + (cur << 13);

        // S^T = mfma(K, Q); Q pre-scaled so sacc is s*0.125*log2e
        floatx4 sacc[8][2] = {};
        #pragma unroll
        for (int kk = 0; kk < 2; kk++)
            #pragma unroll
            for (int mk = 0; mk < 8; mk++) {
                short8 kf = *(const short8*)&Kc[(mk * 16 + c0) * 64 + ((kk * 32 + g * 8) ^ kswz)];
                #pragma unroll
                for (int nq = 0; nq < 2; nq++)
                    sacc[mk][nq] = __builtin_amdgcn_mfma_f32_16x16x32_bf16(kf, qf[nq][kk], sacc[mk][nq], 0, 0, 0);
            }

        // p = exp2(t); l += row-sum
        #pragma unroll
        for (int nq = 0; nq < 2; nq++) {
            float rs = 0.f;
            #pragma unroll
            for (int mk = 0; mk < 8; mk++)
                #pragma unroll
                for (int r = 0; r < 4; r++) {
                    float p = exp2f(sacc[mk][nq][r]);
                    sacc[mk][nq][r] = p;
                    rs += p;
                }
            rs += __shfl_xor(rs, 16);
            rs += __shfl_xor(rs, 32);
            l_run[nq] += rs;
        }

        // PV via x16 MFMA: P is already in B-fragment layout (k = g*4+r)
        #pragma unroll
        for (int mk = 0; mk < 8; mk++) {
            short4v pb[2];
            #pragma unroll
            for (int nq = 0; nq < 2; nq++) {
                union { unsigned int u[2]; short4v s; } pu;
                pu.u[0] = cvtpk(sacc[mk][nq][0], sacc[mk][nq][1]);
                pu.u[1] = cvtpk(sacc[mk][nq][2], sacc[mk][nq][3]);
                pb[nq] = pu.s;
            }
            #pragma unroll
            for (int mk2 = 0; mk2 < 4; mk2++) {
                short4v vf = *(const short4v*)&Vc[(mk2 * 16 + c0) * 128 + ((mk * 16 + g * 4) ^ kswz)];
                #pragma unroll
                for (int nq = 0; nq < 2; nq++)
                    oaccT[mk2][nq] = mfma16(vf, pb[nq], oaccT[mk2][nq]);
            }
        }
        __builtin_amdgcn_sched_barrier(0);
        __builtin_amdgcn_s_barrier();
        __builtin_amdgcn_sched_barrier(0);
    }
#undef STAGE_KV

    const float il[2] = { 1.0f / l_run[0], 1.0f / l_run[1] };

    #pragma unroll
    for (int nq = 0; nq < 2; nq++) {
        int qrow = qt * 128 + wave * 32 + nq * 16 + c0;
        ll row = (ll)b * 2048 + qrow;
        #pragma unroll
        for (int mk2 = 0; mk2 < 4; mk2++) {
            int col = h * 64 + mk2 * 16 + g * 4;
            unsigned int r0 = cvtpk(oaccT[mk2][nq][0] * il[nq], oaccT[mk2][nq][1] * il[nq]);
            unsigned int r1 = cvtpk(oaccT[mk2][nq][2] * il[nq], oaccT[mk2][nq][3] * il[nq]);
            int2 tb = { (int)r0, (int)r1 };
            *(int2*)&attnb[row * 512 + col] = tb;
        }
        if (g == 0) ilbuf[(ll)bh * 2048 + qrow] = il[nq];
    }
}

// ---------------------------------------------------------------------------
// Attention half A: bh 0..15 (256 blocks, XCD-pinned: xcd owns 2 bh)
// ---------------------------------------------------------------------------
__global__ __launch_bounds__(TPB) void attn1a_k(
    const unsigned short* __restrict__ qkv, const unsigned short* __restrict__ vt,
    unsigned short* __restrict__ attnb, float* __restrict__ ilbuf)
{
    __shared__ unsigned short sh[32768];
    const int n = blockIdx.x;
    const int bh = (n & 7) * 2 + ((n >> 3) & 1);
    const int qt = n >> 4;
    attn1_body(qkv, vt, attnb, ilbuf, bh, qt, sh);
}

// ---------------------------------------------------------------------------
// Fused 1: writers bh 0..7 (128 blocks, first) || attention half B bh 16..31
// ---------------------------------------------------------------------------
__global__ __launch_bounds__(TPB) void fused1_k(
    const unsigned short* __restrict__ qkv, const unsigned short* __restrict__ vt,
    unsigned short* __restrict__ attnb, float* __restrict__ ilbuf,
    float* __restrict__ atn)
{
    __shared__ unsigned short sh[32768];
    const int bid = blockIdx.x;
    if (bid < 128) {
        atnwrite_body(qkv, ilbuf, atn, bid & 7, bid >> 3, sh);
    } else {
        const int m = bid - 128;
        const int bh = 16 + (m & 7) * 2 + ((m >> 3) & 1);
        const int qt = m >> 4;
        attn1_body(qkv, vt, attnb, ilbuf, bh, qt, sh);
    }
}

// ---------------------------------------------------------------------------
// Fused GEMM+writers: writer blocks [0, WRCNT*16) for bh WRBH0..WRBH0+WRCNT-1,
// then GX*GY GEMM blocks (XCD-swizzled).
// ---------------------------------------------------------------------------
template<int WRBH0, int WRCNT, int GX, int GY, int BM, int BN, int EPI>
__global__ __launch_bounds__(TPB) void fusedg_k(
    const unsigned short* __restrict__ qkv, const float* __restrict__ ilbuf,
    float* __restrict__ atn,
    const unsigned short* __restrict__ Ap, const unsigned short* __restrict__ BTp,
    const float* __restrict__ bias, void* __restrict__ Cp,
    const unsigned short* __restrict__ Rb,
    int K, ll lda, ll ldb, ll ldc)
{
    __shared__ unsigned short sh[16384];
    const int bid = blockIdx.x;
    constexpr int WRN = WRCNT * 16;
    if (bid < WRN) {
        atnwrite_body(qkv, ilbuf, atn, WRBH0 + bid % WRCNT, bid / WRCNT, sh);
    } else {
        int sid = bid - WRN;
        constexpr int NWG = GX * GY;
        int w = (sid & 7) * (NWG >> 3) + (sid >> 3);
        int bx = w % GX, by = w / GX;
        gemm_body<BM, BN, EPI>(Ap, BTp, bias, Cp, Rb, K, lda, ldb, ldc, bx, by,
                               sh, sh + BM * 64);
    }
}

// ---------------------------------------------------------------------------
// LayerNorm over rows of 512 bf16 -> f32 out (wave per row, 4 rows/block)
// ---------------------------------------------------------------------------
__global__ __launch_bounds__(TPB) void ln_k(const unsigned short* __restrict__ y,
                                            const float* __restrict__ gamma,
                                            const float* __restrict__ beta,
                                            float* __restrict__ out)
{
    const int lane = threadIdx.x & 63;
    const ll row = (ll)blockIdx.x * 4 + (threadIdx.x >> 6);
    short8 v = *(const short8*)(y + row * 512 + lane * 8);
    float f[8];
    float s = 0.f, q = 0.f;
    #pragma unroll
    for (int j = 0; j < 8; j++) {
        f[j] = bu2f((unsigned short)v[j]);
        s += f[j]; q += f[j] * f[j];
    }
    #pragma unroll
    for (int off = 32; off; off >>= 1) { s += __shfl_xor(s, off); q += __shfl_xor(q, off); }
    const float mu  = s * (1.0f / 512.0f);
    const float var = q * (1.0f / 512.0f) - mu * mu;
    const float rs  = rsqrtf(var + 1e-5f);

    float4 g0 = *(const float4*)(gamma + lane * 8);
    float4 g1 = *(const float4*)(gamma + lane * 8 + 4);
    float4 e0 = *(const float4*)(beta  + lane * 8);
    float4 e1 = *(const float4*)(beta  + lane * 8 + 4);
    floatx4 o0, o1;
    o0[0] = (f[0] - mu) * rs * g0.x + e0.x;  o0[1] = (f[1] - mu) * rs * g0.y + e0.y;
    o0[2] = (f[2] - mu) * rs * g0.z + e0.z;  o0[3] = (f[3] - mu) * rs * g0.w + e0.w;
    o1[0] = (f[4] - mu) * rs * g1.x + e1.x;  o1[1] = (f[5] - mu) * rs * g1.y + e1.y;
    o1[2] = (f[6] - mu) * rs * g1.z + e1.z;  o1[3] = (f[7] - mu) * rs * g1.w + e1.w;
    __builtin_nontemporal_store(o0, (floatx4*)(out + row * 512 + lane * 8));
    __builtin_nontemporal_store(o1, (floatx4*)(out + row * 512 + lane * 8 + 4));
}

// ---------------------------------------------------------------------------
// Prep: weight transposes (32x32 tiles) + bias concat + x cast, block-ranged.
// ---------------------------------------------------------------------------
__global__ __launch_bounds__(TPB) void prep_k(
    const float* __restrict__ Wq, const float* __restrict__ Wk,
    const float* __restrict__ Wv, const float* __restrict__ W1,
    const float* __restrict__ W2,
    const float* __restrict__ bq, const float* __restrict__ bk,
    const float* __restrict__ bv, const float* __restrict__ x,
    unsigned short* __restrict__ wtqkv, unsigned short* __restrict__ wt1,
    unsigned short* __restrict__ wt2, float* __restrict__ bqkv,
    unsigned short* __restrict__ xb)
{
    __shared__ float t[32 * 33];
    const int bid = blockIdx.x;
    const float* W; unsigned short* WT; int K, N, tile;
    if (bid < 256)       { W = Wq; WT = wtqkv;             K = 512;  N = 512;  tile = bid; }
    else if (bid < 512)  { W = Wk; WT = wtqkv + 512 * 512; K = 512;  N = 512;  tile = bid - 256; }
    else if (bid < 768)  { W = Wv; WT = wtqkv + 1024 * 512;K = 512;  N = 512;  tile = bid - 512; }
    else if (bid < 1792) { W = W1; WT = wt1;               K = 512;  N = 2048; tile = bid - 768; }
    else if (bid < 2816) { W = W2; WT = wt2;               K = 2048; N = 512;  tile = bid - 1792; }
    else if (bid < 2822) {
        int i = (bid - 2816) * TPB + threadIdx.x;
        if (i < 512)       bqkv[i] = bq[i];
        else if (i < 1024) bqkv[i] = bk[i - 512];
        else if (i < 1536) bqkv[i] = bv[i - 1024];
        return;
    } else {
        ll i = ((ll)(bid - 2822) * TPB + threadIdx.x) * 4;
        float4 v = *(const float4*)(x + i);
        unsigned int r0 = cvtpk(v.x, v.y), r1 = cvtpk(v.z, v.w);
        int2 tt = { (int)r0, (int)r1 };
        *(int2*)(xb + i) = tt;
        return;
    }
    const int nx = N >> 5;
    const int n0 = (tile % nx) * 32, k0 = (tile / nx) * 32;
    const int tx = threadIdx.x & 31, ty = threadIdx.x >> 5;
    #pragma unroll
    for (int i = ty; i < 32; i += 8) t[i * 33 + tx] = W[(ll)(k0 + i) * N + n0 + tx];
    __syncthreads();
    #pragma unroll
    for (int i = ty; i < 32; i += 8) WT[(ll)(n0 + i) * K + k0 + tx] = f2bu(t[tx * 33 + i]);
}

// ---------------------------------------------------------------------------
// V transpose: vt[(b*H+h)*64 + hd][s] = qkv[b*S+s][1024 + h*64 + hd]
// ---------------------------------------------------------------------------
__global__ __launch_bounds__(TPB) void transv_k(const unsigned short* __restrict__ qkv,
                                                unsigned short* __restrict__ vt)
{
    const int z = blockIdx.y;  const int b = z >> 3, h = z & 7;
    const int s0 = blockIdx.x * 64;
    __shared__ unsigned short t[64][72];
    const unsigned short* src = qkv + ((ll)(b * 2048 + s0)) * 1536 + 1024 + h * 64;
    for (int c = threadIdx.x; c < 512; c += TPB) {
        int r = c >> 3, c8 = (c & 7) << 3;
        *(int4*)&t[r][c8] = *(const int4*)(src + (ll)r * 1536 + c8);
    }
    __syncthreads();
    unsigned short* dst = vt + (ll)z * 64 * 2048 + s0;
    for (int c = threadIdx.x; c < 512; c += TPB) {
        int hd = c >> 3, s8 = (c & 7) << 3;
        unsigned short tmp[8];
        #pragma unroll
        for (int j = 0; j < 8; j++) tmp[j] = t[s8 + j][hd];
        *(int4*)(dst + (ll)hd * 2048 + s8) = *(const int4*)tmp;
    }
}

// ---------------------------------------------------------------------------
extern "C" void kernel_launch(void* const* d_in, const int* in_sizes, int n_in,
                              void* d_out, int out_size, void* d_ws, size_t ws_size,
                              hipStream_t stream)
{
    (void)in_sizes; (void)n_in; (void)out_size; (void)ws_size;
    const float* x     = (const float*)d_in[0];
    const float* Wq    = (const float*)d_in[1];
    const float* bq    = (const float*)d_in[2];
    const float* Wk    = (const float*)d_in[3];
    const float* bk    = (const float*)d_in[4];
    const float* Wv    = (const float*)d_in[5];
    const float* bv    = (const float*)d_in[6];
    const float* W1    = (const float*)d_in[7];
    const float* b1    = (const float*)d_in[8];
    const float* W2    = (const float*)d_in[9];
    const float* b2    = (const float*)d_in[10];
    const float* gamma = (const float*)d_in[11];
    const float* beta  = (const float*)d_in[12];

    char* ws = (char*)d_ws;
    size_t off = 0;
    auto alloc = [&](size_t bytes) -> char* {
        char* p = ws + off; off += (bytes + 255) & ~(size_t)255; return p;
    };
    unsigned short* xb    = (unsigned short*)alloc(8192ll * 512 * 2);
    unsigned short* wtqkv = (unsigned short*)alloc(1536ll * 512 * 2);
    unsigned short* wt1   = (unsigned short*)alloc(2048ll * 512 * 2);
    unsigned short* wt2   = (unsigned short*)alloc(512ll * 2048 * 2);
    float*          bqkv  = (float*)alloc(1536 * 4);
    unsigned short* qkv   = (unsigned short*)alloc(8192ll * 1536 * 2);
    unsigned short* vt    = (unsigned short*)alloc(32ll * 64 * 2048 * 2);
    unsigned short* attnb = (unsigned short*)alloc(8192ll * 512 * 2);
    unsigned short* hmid  = (unsigned short*)alloc(8192ll * 2048 * 2);
    unsigned short* ybuf  = (unsigned short*)alloc(8192ll * 512 * 2);
    float*          ilbuf = (float*)alloc(32ll * 2048 * 4);

    float* outp = (float*)d_out;
    float* atn  = outp + 4194304;     // [B,H,S,S] region

    prep_k<<<2822 + 4096, TPB, 0, stream>>>(Wq, Wk, Wv, W1, W2, bq, bk, bv, x,
                                            wtqkv, wt1, wt2, bqkv, xb);

    // QKV: [8192,512] @ [512,1536] -> qkv bf16; Q columns pre-scaled by QSCALE
    gemm_k<128, 128, 7><<<dim3(64, 12, 1), TPB, 0, stream>>>(
        xb, wtqkv, bqkv, qkv, nullptr, 512, 512, 512, 1536);

    transv_k<<<dim3(32, 32), TPB, 0, stream>>>(qkv, vt);

    // Attention half A: bh 0..15 -> attnb + ilbuf
    attn1a_k<<<256, TPB, 0, stream>>>(qkv, vt, attnb, ilbuf);

    // Fused 1: writers bh 0..7 || attention half B (bh 16..31)
    fused1_k<<<384, TPB, 0, stream>>>(qkv, vt, attnb, ilbuf, atn);

    // Fused 2: writers bh 8..19 || FFN1 relu(attn_out@W1+b1) -> hmid
    fusedg_k<8, 12, 64, 16, 128, 128, 3><<<192 + 1024, TPB, 0, stream>>>(
        qkv, ilbuf, atn,
        attnb, wt1, b1, hmid, nullptr, 512, 512, 512, 2048);

    // Fused 3: writers bh 20..31 || FFN2 hmid@W2+b2+attn_out(bf16) -> ybuf bf16
    fusedg_k<20, 12, 128, 4, 64, 128, 6><<<192 + 512, TPB, 0, stream>>>(
        qkv, ilbuf, atn,
        hmid, wt2, b2, ybuf, attnb, 2048, 2048, 2048, 512);

    ln_k<<<2048, TPB, 0, stream>>>(ybuf, gamma, beta, outp);
}

// Round 14
// 271.563 us; speedup vs baseline: 1.3363x; 1.1019x over previous
//
#include <hip/hip_runtime.h>
#include <hip/hip_bf16.h>

#define TPB 256
typedef long long ll;

// B=4, S=2048, D=512, H=8, HD=64, DFF=2048, M=B*S=8192

using short8  = __attribute__((ext_vector_type(8))) short;
using short4v = __attribute__((ext_vector_type(4))) short;
using floatx4 = __attribute__((ext_vector_type(4))) float;

__device__ __forceinline__ unsigned short f2bu(float f) {
    union { float f; unsigned int u; } v; v.f = f;
    unsigned int u = v.u;
    return (unsigned short)((u + 0x7fffu + ((u >> 16) & 1u)) >> 16);  // RNE
}

__device__ __forceinline__ float bu2f(unsigned short us) {
    union { unsigned int u; float f; } v; v.u = ((unsigned int)us) << 16;
    return v.f;
}

// pack two f32 -> one u32 of 2 bf16 (RNE), single HW instruction
__device__ __forceinline__ unsigned int cvtpk(float lo, float hi) {
    unsigned int r;
    asm volatile("v_cvt_pk_bf16_f32 %0, %1, %2" : "=v"(r) : "v"(lo), "v"(hi));
    return r;
}

// 2^x via the HW transcendental (1 instruction; NOT precise-OCML exp2f)
__device__ __forceinline__ float fexp2(float x) {
#if __has_builtin(__builtin_amdgcn_exp2f)
    return __builtin_amdgcn_exp2f(x);
#else
    float r;
    asm("v_exp_f32 %0, %1" : "=v"(r) : "v"(x));
    return r;
#endif
}

// 16x16x16 bf16 MFMA (A,B = 4 bf16 / 2 VGPR per lane)
__device__ __forceinline__ floatx4 mfma16(short4v a, short4v b, floatx4 c) {
#if __has_builtin(__builtin_amdgcn_mfma_f32_16x16x16bf16_1k)
    return __builtin_amdgcn_mfma_f32_16x16x16bf16_1k(a, b, c, 0, 0, 0);
#else
    floatx4 d;
    asm volatile("v_mfma_f32_16x16x16_bf16 %0, %1, %2, %3"
                 : "=v"(d) : "v"(a), "v"(b), "v"(c));
    return d;
#endif
}

__device__ __forceinline__ void gload16(const unsigned short* g, unsigned short* l) {
    __builtin_amdgcn_global_load_lds(
        (const __attribute__((address_space(1))) void*)g,
        (__attribute__((address_space(3))) void*)l, 16, 0, 0);
}

// Q pre-scale: 0.125 * log2(e); attention exps then use 2^x directly.
#define QSCALE 0.18033688f

// ---------------------------------------------------------------------------
// GEMM body (m97 + rule-21 LDS XOR swizzle): C = A[M,K] @ BT[N,K]^T
//   EPI: 0 = bf16+bias ; 3 = bf16+bias+relu ; 6 = bf16+bias+bf16 residual ;
//        7 = bf16+bias, cols<512 scaled by QSCALE (Q pre-scale)
// ---------------------------------------------------------------------------
template<int BM, int BN, int EPI>
__device__ __forceinline__ void gemm_body(
    const unsigned short* __restrict__ Ap, const unsigned short* __restrict__ BTp,
    const float* __restrict__ bias, void* __restrict__ Cp,
    const unsigned short* __restrict__ Rb,
    int K, ll lda, ll ldb, ll ldc, int bx, int by,
    unsigned short* Asm, unsigned short* Bsm)
{
    constexpr int BK = 64;
    const int tid  = threadIdx.x;
    const int lane = tid & 63;
    const int wave = tid >> 6;
    const int wm = wave >> 1, wn = wave & 1;
    constexpr int WM = BM / 2, WN = BN / 2, FM = WM / 16, FN = WN / 16;

    const ll brow = (ll)bx * BM;
    const ll bcol = (ll)by * BN;
    const int srow = lane >> 3;
    const int ssw  = (((lane & 7) ^ srow)) << 3;      // inverse-swizzled col
    const int kswz = (lane & 7) << 3;                 // read-side XOR (shorts)

    floatx4 acc[FM][FN] = {};

    for (int k0 = 0; k0 < K; k0 += BK) {
        #pragma unroll
        for (int ii = 0; ii < BM / 32; ++ii) {
            int i = wave + ii * 4;
            gload16(Ap + (brow + i * 8 + srow) * lda + k0 + ssw, Asm + i * 512);
        }
        #pragma unroll
        for (int ii = 0; ii < BN / 32; ++ii) {
            int i = wave + ii * 4;
            gload16(BTp + (bcol + i * 8 + srow) * ldb + k0 + ssw, Bsm + i * 512);
        }
        __syncthreads();

        #pragma unroll
        for (int kk = 0; kk < BK; kk += 32) {
            short8 af[FM], bfr[FN];
            const int kidx = (kk + ((lane >> 4) << 3)) ^ kswz;
            const int ar = wm * WM + (lane & 15);
            const int bc = wn * WN + (lane & 15);
            #pragma unroll
            for (int m = 0; m < FM; m++)
                af[m] = *(const short8*)&Asm[(ar + m * 16) * BK + kidx];
            #pragma unroll
            for (int n = 0; n < FN; n++)
                bfr[n] = *(const short8*)&Bsm[(bc + n * 16) * BK + kidx];
            #pragma unroll
            for (int m = 0; m < FM; m++)
                #pragma unroll
                for (int n = 0; n < FN; n++)
                    acc[m][n] = __builtin_amdgcn_mfma_f32_16x16x32_bf16(af[m], bfr[n], acc[m][n], 0, 0, 0);
        }
        __syncthreads();
    }

    const ll crow0 = brow + wm * WM + ((lane >> 4) << 2);
    const ll ccol0 = bcol + wn * WN + (lane & 15);
    #pragma unroll
    for (int m = 0; m < FM; m++) {
        #pragma unroll
        for (int j = 0; j < 4; j++) {
            ll row = crow0 + m * 16 + j;
            #pragma unroll
            for (int np = 0; np < FN; np += 2) {
                ll col0 = ccol0 + np * 16;
                ll col1 = col0 + 16;
                float v0 = acc[m][np][j]     + bias[col0];
                float v1 = acc[m][np + 1][j] + bias[col1];
                if constexpr (EPI == 3) {
                    v0 = v0 > 0.f ? v0 : 0.f;
                    v1 = v1 > 0.f ? v1 : 0.f;
                } else if constexpr (EPI == 6) {
                    v0 += bu2f(Rb[row * ldc + col0]);
                    v1 += bu2f(Rb[row * ldc + col1]);
                } else if constexpr (EPI == 7) {
                    if (col0 < 512) v0 *= QSCALE;
                    if (col1 < 512) v1 *= QSCALE;
                }
                unsigned int r = cvtpk(v0, v1);
                ((unsigned short*)Cp)[row * ldc + col0] = (unsigned short)r;
                ((unsigned short*)Cp)[row * ldc + col1] = (unsigned short)(r >> 16);
            }
        }
    }
}

// ---------------------------------------------------------------------------
// Standalone GEMM kernel with m157 XCD swizzle (nwg % 8 == 0)
// ---------------------------------------------------------------------------
template<int BM, int BN, int EPI>
__global__ __launch_bounds__(TPB) void gemm_k(
    const unsigned short* __restrict__ Ap, const unsigned short* __restrict__ BTp,
    const float* __restrict__ bias, void* __restrict__ Cp,
    const unsigned short* __restrict__ Rb,
    int K, ll lda, ll ldb, ll ldc)
{
    __shared__ unsigned short sh[BM * 64 + BN * 64];
    int nwg = gridDim.x * gridDim.y;
    int sid = blockIdx.y * gridDim.x + blockIdx.x;
    int cpx = nwg >> 3;
    int w = (sid & 7) * cpx + (sid >> 3);
    int bx = w % gridDim.x, by = w / gridDim.x;
    gemm_body<BM, BN, EPI>(Ap, BTp, bias, Cp, Rb, K, lda, ldb, ldc, bx, by,
                           sh, sh + BM * 64);
}

// ---------------------------------------------------------------------------
// atn-writer body: per (bh, qt): recompute S^T = mfma(K,Q) (Q pre-scaled by
// 0.125*log2e), write atn = 2^t * il via per-wave LDS transpose ->
// coalesced 512B-run NONTEMPORAL stores (L2-bypass; full 128B lines).
// Uses 32KB of sh.
// ---------------------------------------------------------------------------
__device__ __forceinline__ void atnwrite_body(
    const unsigned short* __restrict__ qkv, const float* __restrict__ ilbuf,
    float* __restrict__ atn, int bh, int qt, unsigned short* sh)
{
    unsigned short* Qsm = sh;
    unsigned short* Ksm = sh + 8192;
    float* Pst = (float*)sh;            // reuses Qsm region after qf extraction

    const int tid = threadIdx.x, lane = tid & 63, wave = tid >> 6;
    const int c0 = lane & 15, g = lane >> 4;
    const int b = bh >> 3, h = bh & 7;

    const ll qbase  = ((ll)(b * 2048 + qt * 128)) * 1536 + h * 64;
    const ll kbase0 = ((ll)(b * 2048)) * 1536 + 512 + h * 64;
    const int srow = lane >> 3;
    const int ssw  = (((lane & 7) ^ srow)) << 3;
    const int kswz = (lane & 7) << 3;

    #pragma unroll
    for (int ii = 0; ii < 4; ++ii) {
        int i = wave + ii * 4;
        gload16(qkv + qbase + (ll)(i * 8 + srow) * 1536 + ssw, Qsm + i * 512);
    }
    __syncthreads();
    short8 qf[2][2];
    #pragma unroll
    for (int nq = 0; nq < 2; nq++)
        #pragma unroll
        for (int kk = 0; kk < 2; kk++)
            qf[nq][kk] = *(const short8*)&Qsm[(wave * 32 + nq * 16 + c0) * 64 + ((kk * 32 + g * 8) ^ kswz)];

    float il2[2];
    #pragma unroll
    for (int nq = 0; nq < 2; nq++)
        il2[nq] = ilbuf[(ll)bh * 2048 + qt * 128 + wave * 32 + nq * 16 + c0];

    float* myP = Pst + wave * 1024;     // [8][128] f32, XOR-swizzled float4 units

    for (int kb = 0; kb < 16; ++kb) {
        const ll koff = kbase0 + (ll)kb * 128 * 1536;
        #pragma unroll
        for (int ii = 0; ii < 4; ++ii) {
            int i = wave + ii * 4;
            gload16(qkv + koff + (ll)(i * 8 + srow) * 1536 + ssw, Ksm + i * 512);
        }
        __syncthreads();

        floatx4 sacc[8][2] = {};
        #pragma unroll
        for (int kk = 0; kk < 2; kk++)
            #pragma unroll
            for (int mk = 0; mk < 8; mk++) {
                short8 kf = *(const short8*)&Ksm[(mk * 16 + c0) * 64 + ((kk * 32 + g * 8) ^ kswz)];
                #pragma unroll
                for (int nq = 0; nq < 2; nq++)
                    sacc[mk][nq] = __builtin_amdgcn_mfma_f32_16x16x32_bf16(kf, qf[nq][kk], sacc[mk][nq], 0, 0, 0);
            }

        #pragma unroll
        for (int mk = 0; mk < 8; mk++)
            #pragma unroll
            for (int nq = 0; nq < 2; nq++)
                #pragma unroll
                for (int r = 0; r < 4; r++)
                    sacc[mk][nq][r] = fexp2(sacc[mk][nq][r]) * il2[nq];

        #pragma unroll
        for (int nq = 0; nq < 2; nq++) {
            #pragma unroll
            for (int hf = 0; hf < 2; hf++) {
                if ((c0 >> 3) == hf) {
                    int rho = c0 & 7;
                    #pragma unroll
                    for (int mk = 0; mk < 8; mk++) {
                        int k4 = mk * 4 + g;
                        ((floatx4*)myP)[rho * 32 + (k4 ^ rho)] = sacc[mk][nq];
                    }
                }
                const ll grow = (ll)bh * 2048 + qt * 128 + wave * 32 + nq * 16 + hf * 8;
                #pragma unroll
                for (int t = 0; t < 4; t++) {
                    int rr = t * 2 + (lane >> 5);
                    int k4r = lane & 31;
                    floatx4 v = ((const floatx4*)myP)[rr * 32 + (k4r ^ rr)];
                    __builtin_nontemporal_store(
                        v, (floatx4*)(atn + (grow + rr) * 2048 + kb * 128 + k4r * 4));
                }
            }
        }
        __syncthreads();
    }
}

// ---------------------------------------------------------------------------
// Attention pass 1 body: per (bh, qt): double-buffered K/V (counted vmcnt(8),
// raw s_barrier), no-max 2^x softmax (pre-scaled Q), x16-MFMA PV.
// Uses 64KB of sh (Kbuf0|Kbuf1|Vbuf0|Vbuf1, 16KB each).
// ---------------------------------------------------------------------------
__device__ __forceinline__ void attn1_body(
    const unsigned short* __restrict__ qkv, const unsigned short* __restrict__ vt,
    unsigned short* __restrict__ attnb, float* __restrict__ ilbuf,
    int bh, int qt, unsigned short* sh)
{
    const int tid = threadIdx.x, lane = tid & 63, wave = tid >> 6;
    const int c0 = lane & 15, g = lane >> 4;
    const int srow = lane >> 3;
    const int ssw  = (((lane & 7) ^ srow)) << 3;
    const int kswz = (lane & 7) << 3;
    const int b = bh >> 3, h = bh & 7;

    const ll qbase  = ((ll)(b * 2048 + qt * 128)) * 1536 + h * 64;
    const ll kbase0 = ((ll)(b * 2048)) * 1536 + 512 + h * 64;
    const unsigned short* vbase = vt + (ll)bh * 64 * 2048;

    // stage Q [128][64] into buf0 (swizzled), pull B-fragments to registers
    #pragma unroll
    for (int ii = 0; ii < 4; ++ii) {
        int i = wave + ii * 4;
        gload16(qkv + qbase + (ll)(i * 8 + srow) * 1536 + ssw, sh + i * 512);
    }
    __syncthreads();
    short8 qf[2][2];
    #pragma unroll
    for (int nq = 0; nq < 2; nq++)
        #pragma unroll
        for (int kk = 0; kk < 2; kk++)
            qf[nq][kk] = *(const short8*)&sh[(wave * 32 + nq * 16 + c0) * 64 + ((kk * 32 + g * 8) ^ kswz)];
    __syncthreads();

    floatx4 oaccT[4][2] = {};
    float l_run[2] = {0.f, 0.f};

#define STAGE_KV(kbx, bb) do {                                                   \
    const ll koff_ = kbase0 + (ll)(kbx) * 128 * 1536;                            \
    unsigned short* Kd_ = sh + ((bb) << 13);                                     \
    unsigned short* Vd_ = sh + 16384 + ((bb) << 13);                             \
    _Pragma("unroll")                                                            \
    for (int ii = 0; ii < 4; ++ii) { int i = wave + ii * 4;                      \
        gload16(qkv + koff_ + (ll)(i * 8 + srow) * 1536 + ssw, Kd_ + i * 512); } \
    _Pragma("unroll")                                                            \
    for (int ii = 0; ii < 4; ++ii) { int i = wave + ii * 4; int s = i * 8 + srow;\
        int vrow = s >> 1; int vslot = ((s & 1) << 3) | (lane & 7);              \
        gload16(vbase + (ll)vrow * 2048 + (kbx) * 128 + ((vslot ^ (vrow & 7)) << 3), \
                Vd_ + i * 512); }                                                \
} while (0)

    STAGE_KV(0, 0);
    for (int kb = 0; kb < 16; ++kb) {
        const int cur = kb & 1;
        if (kb < 15) {
            STAGE_KV(kb + 1, cur ^ 1);
            asm volatile("s_waitcnt vmcnt(8)" ::: "memory");
        } else {
            asm volatile("s_waitcnt vmcnt(0)" ::: "memory");
        }
        __builtin_amdgcn_sched_barrier(0);
        __builtin_amdgcn_s_barrier();
        __builtin_amdgcn_sched_barrier(0);

        unsigned short* Kc = sh + (cur << 13);
        unsigned short* Vc = sh + 16384 + (cur << 13);

        // S^T = mfma(K, Q); Q pre-scaled so sacc is s*0.125*log2e
        floatx4 sacc[8][2] = {};
        #pragma unroll
        for (int kk = 0; kk < 2; kk++)
            #pragma unroll
            for (int mk = 0; mk < 8; mk++) {
                short8 kf = *(const short8*)&Kc[(mk * 16 + c0) * 64 + ((kk * 32 + g * 8) ^ kswz)];
                #pragma unroll
                for (int nq = 0; nq < 2; nq++)
                    sacc[mk][nq] = __builtin_amdgcn_mfma_f32_16x16x32_bf16(kf, qf[nq][kk], sacc[mk][nq], 0, 0, 0);
            }

        // p = 2^t; l += row-sum
        #pragma unroll
        for (int nq = 0; nq < 2; nq++) {
            float rs = 0.f;
            #pragma unroll
            for (int mk = 0; mk < 8; mk++)
                #pragma unroll
                for (int r = 0; r < 4; r++) {
                    float p = fexp2(sacc[mk][nq][r]);
                    sacc[mk][nq][r] = p;
                    rs += p;
                }
            rs += __shfl_xor(rs, 16);
            rs += __shfl_xor(rs, 32);
            l_run[nq] += rs;
        }

        // PV via x16 MFMA: P is already in B-fragment layout (k = g*4+r)
        #pragma unroll
        for (int mk = 0; mk < 8; mk++) {
            short4v pb[2];
            #pragma unroll
            for (int nq = 0; nq < 2; nq++) {
                union { unsigned int u[2]; short4v s; } pu;
                pu.u[0] = cvtpk(sacc[mk][nq][0], sacc[mk][nq][1]);
                pu.u[1] = cvtpk(sacc[mk][nq][2], sacc[mk][nq][3]);
                pb[nq] = pu.s;
            }
            #pragma unroll
            for (int mk2 = 0; mk2 < 4; mk2++) {
                short4v vf = *(const short4v*)&Vc[(mk2 * 16 + c0) * 128 + ((mk * 16 + g * 4) ^ kswz)];
                #pragma unroll
                for (int nq = 0; nq < 2; nq++)
                    oaccT[mk2][nq] = mfma16(vf, pb[nq], oaccT[mk2][nq]);
            }
        }
        __builtin_amdgcn_sched_barrier(0);
        __builtin_amdgcn_s_barrier();
        __builtin_amdgcn_sched_barrier(0);
    }
#undef STAGE_KV

    const float il[2] = { 1.0f / l_run[0], 1.0f / l_run[1] };

    #pragma unroll
    for (int nq = 0; nq < 2; nq++) {
        int qrow = qt * 128 + wave * 32 + nq * 16 + c0;
        ll row = (ll)b * 2048 + qrow;
        #pragma unroll
        for (int mk2 = 0; mk2 < 4; mk2++) {
            int col = h * 64 + mk2 * 16 + g * 4;
            unsigned int r0 = cvtpk(oaccT[mk2][nq][0] * il[nq], oaccT[mk2][nq][1] * il[nq]);
            unsigned int r1 = cvtpk(oaccT[mk2][nq][2] * il[nq], oaccT[mk2][nq][3] * il[nq]);
            int2 tb = { (int)r0, (int)r1 };
            *(int2*)&attnb[row * 512 + col] = tb;
        }
        if (g == 0) ilbuf[(ll)bh * 2048 + qrow] = il[nq];
    }
}

// ---------------------------------------------------------------------------
// Attention half A: bh 0..15 (256 blocks, XCD-pinned: xcd owns 2 bh)
// ---------------------------------------------------------------------------
__global__ __launch_bounds__(TPB) void attn1a_k(
    const unsigned short* __restrict__ qkv, const unsigned short* __restrict__ vt,
    unsigned short* __restrict__ attnb, float* __restrict__ ilbuf)
{
    __shared__ unsigned short sh[32768];
    const int n = blockIdx.x;
    const int bh = (n & 7) * 2 + ((n >> 3) & 1);
    const int qt = n >> 4;
    attn1_body(qkv, vt, attnb, ilbuf, bh, qt, sh);
}

// ---------------------------------------------------------------------------
// Fused 1: writers bh 0..7 (128 blocks, first) || attention half B bh 16..31
// ---------------------------------------------------------------------------
__global__ __launch_bounds__(TPB) void fused1_k(
    const unsigned short* __restrict__ qkv, const unsigned short* __restrict__ vt,
    unsigned short* __restrict__ attnb, float* __restrict__ ilbuf,
    float* __restrict__ atn)
{
    __shared__ unsigned short sh[32768];
    const int bid = blockIdx.x;
    if (bid < 128) {
        atnwrite_body(qkv, ilbuf, atn, bid & 7, bid >> 3, sh);
    } else {
        const int m = bid - 128;
        const int bh = 16 + (m & 7) * 2 + ((m >> 3) & 1);
        const int qt = m >> 4;
        attn1_body(qkv, vt, attnb, ilbuf, bh, qt, sh);
    }
}

// ---------------------------------------------------------------------------
// Fused GEMM+writers: writer blocks [0, WRCNT*16) for bh WRBH0..WRBH0+WRCNT-1,
// then GX*GY GEMM blocks (XCD-swizzled).
// ---------------------------------------------------------------------------
template<int WRBH0, int WRCNT, int GX, int GY, int BM, int BN, int EPI>
__global__ __launch_bounds__(TPB) void fusedg_k(
    const unsigned short* __restrict__ qkv, const float* __restrict__ ilbuf,
    float* __restrict__ atn,
    const unsigned short* __restrict__ Ap, const unsigned short* __restrict__ BTp,
    const float* __restrict__ bias, void* __restrict__ Cp,
    const unsigned short* __restrict__ Rb,
    int K, ll lda, ll ldb, ll ldc)
{
    __shared__ unsigned short sh[16384];
    const int bid = blockIdx.x;
    constexpr int WRN = WRCNT * 16;
    if (bid < WRN) {
        atnwrite_body(qkv, ilbuf, atn, WRBH0 + bid % WRCNT, bid / WRCNT, sh);
    } else {
        int sid = bid - WRN;
        constexpr int NWG = GX * GY;
        int w = (sid & 7) * (NWG >> 3) + (sid >> 3);
        int bx = w % GX, by = w / GX;
        gemm_body<BM, BN, EPI>(Ap, BTp, bias, Cp, Rb, K, lda, ldb, ldc, bx, by,
                               sh, sh + BM * 64);
    }
}

// ---------------------------------------------------------------------------
// LayerNorm over rows of 512 bf16 -> f32 out (wave per row, 4 rows/block)
// ---------------------------------------------------------------------------
__global__ __launch_bounds__(TPB) void ln_k(const unsigned short* __restrict__ y,
                                            const float* __restrict__ gamma,
                                            const float* __restrict__ beta,
                                            float* __restrict__ out)
{
    const int lane = threadIdx.x & 63;
    const ll row = (ll)blockIdx.x * 4 + (threadIdx.x >> 6);
    short8 v = *(const short8*)(y + row * 512 + lane * 8);
    float f[8];
    float s = 0.f, q = 0.f;
    #pragma unroll
    for (int j = 0; j < 8; j++) {
        f[j] = bu2f((unsigned short)v[j]);
        s += f[j]; q += f[j] * f[j];
    }
    #pragma unroll
    for (int off = 32; off; off >>= 1) { s += __shfl_xor(s, off); q += __shfl_xor(q, off); }
    const float mu  = s * (1.0f / 512.0f);
    const float var = q * (1.0f / 512.0f) - mu * mu;
    const float rs  = rsqrtf(var + 1e-5f);

    float4 g0 = *(const float4*)(gamma + lane * 8);
    float4 g1 = *(const float4*)(gamma + lane * 8 + 4);
    float4 e0 = *(const float4*)(beta  + lane * 8);
    float4 e1 = *(const float4*)(beta  + lane * 8 + 4);
    floatx4 o0, o1;
    o0[0] = (f[0] - mu) * rs * g0.x + e0.x;  o0[1] = (f[1] - mu) * rs * g0.y + e0.y;
    o0[2] = (f[2] - mu) * rs * g0.z + e0.z;  o0[3] = (f[3] - mu) * rs * g0.w + e0.w;
    o1[0] = (f[4] - mu) * rs * g1.x + e1.x;  o1[1] = (f[5] - mu) * rs * g1.y + e1.y;
    o1[2] = (f[6] - mu) * rs * g1.z + e1.z;  o1[3] = (f[7] - mu) * rs * g1.w + e1.w;
    __builtin_nontemporal_store(o0, (floatx4*)(out + row * 512 + lane * 8));
    __builtin_nontemporal_store(o1, (floatx4*)(out + row * 512 + lane * 8 + 4));
}

// ---------------------------------------------------------------------------
// Prep: weight transposes (32x32 tiles) + bias concat + x cast, block-ranged.
// ---------------------------------------------------------------------------
__global__ __launch_bounds__(TPB) void prep_k(
    const float* __restrict__ Wq, const float* __restrict__ Wk,
    const float* __restrict__ Wv, const float* __restrict__ W1,
    const float* __restrict__ W2,
    const float* __restrict__ bq, const float* __restrict__ bk,
    const float* __restrict__ bv, const float* __restrict__ x,
    unsigned short* __restrict__ wtqkv, unsigned short* __restrict__ wt1,
    unsigned short* __restrict__ wt2, float* __restrict__ bqkv,
    unsigned short* __restrict__ xb)
{
    __shared__ float t[32 * 33];
    const int bid = blockIdx.x;
    const float* W; unsigned short* WT; int K, N, tile;
    if (bid < 256)       { W = Wq; WT = wtqkv;             K = 512;  N = 512;  tile = bid; }
    else if (bid < 512)  { W = Wk; WT = wtqkv + 512 * 512; K = 512;  N = 512;  tile = bid - 256; }
    else if (bid < 768)  { W = Wv; WT = wtqkv + 1024 * 512;K = 512;  N = 512;  tile = bid - 512; }
    else if (bid < 1792) { W = W1; WT = wt1;               K = 512;  N = 2048; tile = bid - 768; }
    else if (bid < 2816) { W = W2; WT = wt2;               K = 2048; N = 512;  tile = bid - 1792; }
    else if (bid < 2822) {
        int i = (bid - 2816) * TPB + threadIdx.x;
        if (i < 512)       bqkv[i] = bq[i];
        else if (i < 1024) bqkv[i] = bk[i - 512];
        else if (i < 1536) bqkv[i] = bv[i - 1024];
        return;
    } else {
        ll i = ((ll)(bid - 2822) * TPB + threadIdx.x) * 4;
        float4 v = *(const float4*)(x + i);
        unsigned int r0 = cvtpk(v.x, v.y), r1 = cvtpk(v.z, v.w);
        int2 tt = { (int)r0, (int)r1 };
        *(int2*)(xb + i) = tt;
        return;
    }
    const int nx = N >> 5;
    const int n0 = (tile % nx) * 32, k0 = (tile / nx) * 32;
    const int tx = threadIdx.x & 31, ty = threadIdx.x >> 5;
    #pragma unroll
    for (int i = ty; i < 32; i += 8) t[i * 33 + tx] = W[(ll)(k0 + i) * N + n0 + tx];
    __syncthreads();
    #pragma unroll
    for (int i = ty; i < 32; i += 8) WT[(ll)(n0 + i) * K + k0 + tx] = f2bu(t[tx * 33 + i]);
}

// ---------------------------------------------------------------------------
// V transpose: vt[(b*H+h)*64 + hd][s] = qkv[b*S+s][1024 + h*64 + hd]
// ---------------------------------------------------------------------------
__global__ __launch_bounds__(TPB) void transv_k(const unsigned short* __restrict__ qkv,
                                                unsigned short* __restrict__ vt)
{
    const int z = blockIdx.y;  const int b = z >> 3, h = z & 7;
    const int s0 = blockIdx.x * 64;
    __shared__ unsigned short t[64][72];
    const unsigned short* src = qkv + ((ll)(b * 2048 + s0)) * 1536 + 1024 + h * 64;
    for (int c = threadIdx.x; c < 512; c += TPB) {
        int r = c >> 3, c8 = (c & 7) << 3;
        *(int4*)&t[r][c8] = *(const int4*)(src + (ll)r * 1536 + c8);
    }
    __syncthreads();
    unsigned short* dst = vt + (ll)z * 64 * 2048 + s0;
    for (int c = threadIdx.x; c < 512; c += TPB) {
        int hd = c >> 3, s8 = (c & 7) << 3;
        unsigned short tmp[8];
        #pragma unroll
        for (int j = 0; j < 8; j++) tmp[j] = t[s8 + j][hd];
        *(int4*)(dst + (ll)hd * 2048 + s8) = *(const int4*)tmp;
    }
}

// ---------------------------------------------------------------------------
extern "C" void kernel_launch(void* const* d_in, const int* in_sizes, int n_in,
                              void* d_out, int out_size, void* d_ws, size_t ws_size,
                              hipStream_t stream)
{
    (void)in_sizes; (void)n_in; (void)out_size; (void)ws_size;
    const float* x     = (const float*)d_in[0];
    const float* Wq    = (const float*)d_in[1];
    const float* bq    = (const float*)d_in[2];
    const float* Wk    = (const float*)d_in[3];
    const float* bk    = (const float*)d_in[4];
    const float* Wv    = (const float*)d_in[5];
    const float* bv    = (const float*)d_in[6];
    const float* W1    = (const float*)d_in[7];
    const float* b1    = (const float*)d_in[8];
    const float* W2    = (const float*)d_in[9];
    const float* b2    = (const float*)d_in[10];
    const float* gamma = (const float*)d_in[11];
    const float* beta  = (const float*)d_in[12];

    char* ws = (char*)d_ws;
    size_t off = 0;
    auto alloc = [&](size_t bytes) -> char* {
        char* p = ws + off; off += (bytes + 255) & ~(size_t)255; return p;
    };
    unsigned short* xb    = (unsigned short*)alloc(8192ll * 512 * 2);
    unsigned short* wtqkv = (unsigned short*)alloc(1536ll * 512 * 2);
    unsigned short* wt1   = (unsigned short*)alloc(2048ll * 512 * 2);
    unsigned short* wt2   = (unsigned short*)alloc(512ll * 2048 * 2);
    float*          bqkv  = (float*)alloc(1536 * 4);
    unsigned short* qkv   = (unsigned short*)alloc(8192ll * 1536 * 2);
    unsigned short* vt    = (unsigned short*)alloc(32ll * 64 * 2048 * 2);
    unsigned short* attnb = (unsigned short*)alloc(8192ll * 512 * 2);
    unsigned short* hmid  = (unsigned short*)alloc(8192ll * 2048 * 2);
    unsigned short* ybuf  = (unsigned short*)alloc(8192ll * 512 * 2);
    float*          ilbuf = (float*)alloc(32ll * 2048 * 4);

    float* outp = (float*)d_out;
    float* atn  = outp + 4194304;     // [B,H,S,S] region

    prep_k<<<2822 + 4096, TPB, 0, stream>>>(Wq, Wk, Wv, W1, W2, bq, bk, bv, x,
                                            wtqkv, wt1, wt2, bqkv, xb);

    // QKV: [8192,512] @ [512,1536] -> qkv bf16; Q columns pre-scaled by QSCALE
    gemm_k<128, 128, 7><<<dim3(64, 12, 1), TPB, 0, stream>>>(
        xb, wtqkv, bqkv, qkv, nullptr, 512, 512, 512, 1536);

    transv_k<<<dim3(32, 32), TPB, 0, stream>>>(qkv, vt);

    // Attention half A: bh 0..15 -> attnb + ilbuf
    attn1a_k<<<256, TPB, 0, stream>>>(qkv, vt, attnb, ilbuf);

    // Fused 1: writers bh 0..7 || attention half B (bh 16..31)
    fused1_k<<<384, TPB, 0, stream>>>(qkv, vt, attnb, ilbuf, atn);

    // Fused 2: writers bh 8..19 || FFN1 relu(attn_out@W1+b1) -> hmid
    fusedg_k<8, 12, 64, 16, 128, 128, 3><<<192 + 1024, TPB, 0, stream>>>(
        qkv, ilbuf, atn,
        attnb, wt1, b1, hmid, nullptr, 512, 512, 512, 2048);

    // Fused 3: writers bh 20..31 || FFN2 hmid@W2+b2+attn_out(bf16) -> ybuf bf16
    fusedg_k<20, 12, 128, 4, 64, 128, 6><<<192 + 512, TPB, 0, stream>>>(
        qkv, ilbuf, atn,
        hmid, wt2, b2, ybuf, attnb, 2048, 2048, 2048, 512);

    ln_k<<<2048, TPB, 0, stream>>>(ybuf, gamma, beta, outp);
}

// Round 15
// 258.544 us; speedup vs baseline: 1.4035x; 1.0504x over previous
//
#include <hip/hip_runtime.h>
#include <hip/hip_bf16.h>

#define TPB 256
typedef long long ll;

// B=4, S=2048, D=512, H=8, HD=64, DFF=2048, M=B*S=8192

using short8  = __attribute__((ext_vector_type(8))) short;
using short4v = __attribute__((ext_vector_type(4))) short;
using floatx4 = __attribute__((ext_vector_type(4))) float;

__device__ __forceinline__ unsigned short f2bu(float f) {
    union { float f; unsigned int u; } v; v.f = f;
    unsigned int u = v.u;
    return (unsigned short)((u + 0x7fffu + ((u >> 16) & 1u)) >> 16);  // RNE
}

__device__ __forceinline__ float bu2f(unsigned short us) {
    union { unsigned int u; float f; } v; v.u = ((unsigned int)us) << 16;
    return v.f;
}

// pack two f32 -> one u32 of 2 bf16 (RNE), single HW instruction
__device__ __forceinline__ unsigned int cvtpk(float lo, float hi) {
    unsigned int r;
    asm volatile("v_cvt_pk_bf16_f32 %0, %1, %2" : "=v"(r) : "v"(lo), "v"(hi));
    return r;
}

// 2^x via the HW transcendental (1 instruction; NOT precise-OCML exp2f)
__device__ __forceinline__ float fexp2(float x) {
#if __has_builtin(__builtin_amdgcn_exp2f)
    return __builtin_amdgcn_exp2f(x);
#else
    float r;
    asm("v_exp_f32 %0, %1" : "=v"(r) : "v"(x));
    return r;
#endif
}

// 16x16x16 bf16 MFMA (A,B = 4 bf16 / 2 VGPR per lane)
__device__ __forceinline__ floatx4 mfma16(short4v a, short4v b, floatx4 c) {
#if __has_builtin(__builtin_amdgcn_mfma_f32_16x16x16bf16_1k)
    return __builtin_amdgcn_mfma_f32_16x16x16bf16_1k(a, b, c, 0, 0, 0);
#else
    floatx4 d;
    asm volatile("v_mfma_f32_16x16x16_bf16 %0, %1, %2, %3"
                 : "=v"(d) : "v"(a), "v"(b), "v"(c));
    return d;
#endif
}

__device__ __forceinline__ void gload16(const unsigned short* g, unsigned short* l) {
    __builtin_amdgcn_global_load_lds(
        (const __attribute__((address_space(1))) void*)g,
        (__attribute__((address_space(3))) void*)l, 16, 0, 0);
}

// Q pre-scale: 0.125 * log2(e); attention exps then use 2^x directly.
#define QSCALE 0.18033688f

// ---------------------------------------------------------------------------
// GEMM body (m97 + rule-21 LDS XOR swizzle): C = A[M,K] @ BT[N,K]^T
//   EPI: 0 = bf16+bias ; 3 = bf16+bias+relu ; 6 = bf16+bias+bf16 residual ;
//        7 = QKV: cols<512 scaled by QSCALE; cols>=1024 (V) written
//            TRANSPOSED to Vtp (vt[b,h,hd][s]) instead of Cp.
// ---------------------------------------------------------------------------
template<int BM, int BN, int EPI>
__device__ __forceinline__ void gemm_body(
    const unsigned short* __restrict__ Ap, const unsigned short* __restrict__ BTp,
    const float* __restrict__ bias, void* __restrict__ Cp,
    const unsigned short* __restrict__ Rb, unsigned short* __restrict__ Vtp,
    int K, ll lda, ll ldb, ll ldc, int bx, int by,
    unsigned short* Asm, unsigned short* Bsm)
{
    constexpr int BK = 64;
    const int tid  = threadIdx.x;
    const int lane = tid & 63;
    const int wave = tid >> 6;
    const int wm = wave >> 1, wn = wave & 1;
    constexpr int WM = BM / 2, WN = BN / 2, FM = WM / 16, FN = WN / 16;

    const ll brow = (ll)bx * BM;
    const ll bcol = (ll)by * BN;
    const int srow = lane >> 3;
    const int ssw  = (((lane & 7) ^ srow)) << 3;      // inverse-swizzled col
    const int kswz = (lane & 7) << 3;                 // read-side XOR (shorts)

    floatx4 acc[FM][FN] = {};

    for (int k0 = 0; k0 < K; k0 += BK) {
        #pragma unroll
        for (int ii = 0; ii < BM / 32; ++ii) {
            int i = wave + ii * 4;
            gload16(Ap + (brow + i * 8 + srow) * lda + k0 + ssw, Asm + i * 512);
        }
        #pragma unroll
        for (int ii = 0; ii < BN / 32; ++ii) {
            int i = wave + ii * 4;
            gload16(BTp + (bcol + i * 8 + srow) * ldb + k0 + ssw, Bsm + i * 512);
        }
        __syncthreads();

        #pragma unroll
        for (int kk = 0; kk < BK; kk += 32) {
            short8 af[FM], bfr[FN];
            const int kidx = (kk + ((lane >> 4) << 3)) ^ kswz;
            const int ar = wm * WM + (lane & 15);
            const int bc = wn * WN + (lane & 15);
            #pragma unroll
            for (int m = 0; m < FM; m++)
                af[m] = *(const short8*)&Asm[(ar + m * 16) * BK + kidx];
            #pragma unroll
            for (int n = 0; n < FN; n++)
                bfr[n] = *(const short8*)&Bsm[(bc + n * 16) * BK + kidx];
            #pragma unroll
            for (int m = 0; m < FM; m++)
                #pragma unroll
                for (int n = 0; n < FN; n++)
                    acc[m][n] = __builtin_amdgcn_mfma_f32_16x16x32_bf16(af[m], bfr[n], acc[m][n], 0, 0, 0);
        }
        __syncthreads();
    }

    const ll crow0 = brow + wm * WM + ((lane >> 4) << 2);
    const ll ccol0 = bcol + wn * WN + (lane & 15);

    if constexpr (EPI == 7) {
        if (ccol0 >= 1024) {
            // V block: write transposed to vt[(b*8+h)*64+hd][s] as bf16
            const int bz = (int)(brow >> 11);
            #pragma unroll
            for (int m = 0; m < FM; m++) {
                const int sl = (int)((crow0 + m * 16) & 2047);
                #pragma unroll
                for (int n = 0; n < FN; n++) {
                    const int col = (int)(ccol0 + n * 16);
                    const float bv = bias[col];
                    const int hdg = col - 1024;
                    unsigned int u0 = cvtpk(acc[m][n][0] + bv, acc[m][n][1] + bv);
                    unsigned int u1 = cvtpk(acc[m][n][2] + bv, acc[m][n][3] + bv);
                    int2 t = { (int)u0, (int)u1 };
                    *(int2*)(Vtp + ((ll)((bz * 8 + (hdg >> 6)) * 64 + (hdg & 63))) * 2048 + sl) = t;
                }
            }
            return;
        }
    }

    #pragma unroll
    for (int m = 0; m < FM; m++) {
        #pragma unroll
        for (int j = 0; j < 4; j++) {
            ll row = crow0 + m * 16 + j;
            #pragma unroll
            for (int np = 0; np < FN; np += 2) {
                ll col0 = ccol0 + np * 16;
                ll col1 = col0 + 16;
                float v0 = acc[m][np][j]     + bias[col0];
                float v1 = acc[m][np + 1][j] + bias[col1];
                if constexpr (EPI == 3) {
                    v0 = v0 > 0.f ? v0 : 0.f;
                    v1 = v1 > 0.f ? v1 : 0.f;
                } else if constexpr (EPI == 6) {
                    v0 += bu2f(Rb[row * ldc + col0]);
                    v1 += bu2f(Rb[row * ldc + col1]);
                } else if constexpr (EPI == 7) {
                    if (col0 < 512) v0 *= QSCALE;
                    if (col1 < 512) v1 *= QSCALE;
                }
                unsigned int r = cvtpk(v0, v1);
                ((unsigned short*)Cp)[row * ldc + col0] = (unsigned short)r;
                ((unsigned short*)Cp)[row * ldc + col1] = (unsigned short)(r >> 16);
            }
        }
    }
}

// ---------------------------------------------------------------------------
// Standalone GEMM kernel with m157 XCD swizzle (nwg % 8 == 0)
// ---------------------------------------------------------------------------
template<int BM, int BN, int EPI>
__global__ __launch_bounds__(TPB) void gemm_k(
    const unsigned short* __restrict__ Ap, const unsigned short* __restrict__ BTp,
    const float* __restrict__ bias, void* __restrict__ Cp,
    const unsigned short* __restrict__ Rb, unsigned short* __restrict__ Vtp,
    int K, ll lda, ll ldb, ll ldc)
{
    __shared__ unsigned short sh[BM * 64 + BN * 64];
    int nwg = gridDim.x * gridDim.y;
    int sid = blockIdx.y * gridDim.x + blockIdx.x;
    int cpx = nwg >> 3;
    int w = (sid & 7) * cpx + (sid >> 3);
    int bx = w % gridDim.x, by = w / gridDim.x;
    gemm_body<BM, BN, EPI>(Ap, BTp, bias, Cp, Rb, Vtp, K, lda, ldb, ldc, bx, by,
                           sh, sh + BM * 64);
}

// ---------------------------------------------------------------------------
// atn-writer body: per (bh, qt): recompute S^T = mfma(K,Q) (Q pre-scaled by
// 0.125*log2e), write atn = 2^t * il via per-wave LDS transpose ->
// coalesced 512B-run NONTEMPORAL stores. Uses 32KB of sh. (4-wave body)
// ---------------------------------------------------------------------------
__device__ __forceinline__ void atnwrite_body(
    const unsigned short* __restrict__ qkv, const float* __restrict__ ilbuf,
    float* __restrict__ atn, int bh, int qt, unsigned short* sh)
{
    unsigned short* Qsm = sh;
    unsigned short* Ksm = sh + 8192;
    float* Pst = (float*)sh;            // reuses Qsm region after qf extraction

    const int tid = threadIdx.x, lane = tid & 63, wave = tid >> 6;
    const int c0 = lane & 15, g = lane >> 4;
    const int b = bh >> 3, h = bh & 7;

    const ll qbase  = ((ll)(b * 2048 + qt * 128)) * 1536 + h * 64;
    const ll kbase0 = ((ll)(b * 2048)) * 1536 + 512 + h * 64;
    const int srow = lane >> 3;
    const int ssw  = (((lane & 7) ^ srow)) << 3;
    const int kswz = (lane & 7) << 3;

    #pragma unroll
    for (int ii = 0; ii < 4; ++ii) {
        int i = wave + ii * 4;
        gload16(qkv + qbase + (ll)(i * 8 + srow) * 1536 + ssw, Qsm + i * 512);
    }
    __syncthreads();
    short8 qf[2][2];
    #pragma unroll
    for (int nq = 0; nq < 2; nq++)
        #pragma unroll
        for (int kk = 0; kk < 2; kk++)
            qf[nq][kk] = *(const short8*)&Qsm[(wave * 32 + nq * 16 + c0) * 64 + ((kk * 32 + g * 8) ^ kswz)];

    float il2[2];
    #pragma unroll
    for (int nq = 0; nq < 2; nq++)
        il2[nq] = ilbuf[(ll)bh * 2048 + qt * 128 + wave * 32 + nq * 16 + c0];

    float* myP = Pst + wave * 1024;     // [8][128] f32, XOR-swizzled float4 units

    for (int kb = 0; kb < 16; ++kb) {
        const ll koff = kbase0 + (ll)kb * 128 * 1536;
        #pragma unroll
        for (int ii = 0; ii < 4; ++ii) {
            int i = wave + ii * 4;
            gload16(qkv + koff + (ll)(i * 8 + srow) * 1536 + ssw, Ksm + i * 512);
        }
        __syncthreads();

        floatx4 sacc[8][2] = {};
        #pragma unroll
        for (int kk = 0; kk < 2; kk++)
            #pragma unroll
            for (int mk = 0; mk < 8; mk++) {
                short8 kf = *(const short8*)&Ksm[(mk * 16 + c0) * 64 + ((kk * 32 + g * 8) ^ kswz)];
                #pragma unroll
                for (int nq = 0; nq < 2; nq++)
                    sacc[mk][nq] = __builtin_amdgcn_mfma_f32_16x16x32_bf16(kf, qf[nq][kk], sacc[mk][nq], 0, 0, 0);
            }

        #pragma unroll
        for (int mk = 0; mk < 8; mk++)
            #pragma unroll
            for (int nq = 0; nq < 2; nq++)
                #pragma unroll
                for (int r = 0; r < 4; r++)
                    sacc[mk][nq][r] = fexp2(sacc[mk][nq][r]) * il2[nq];

        #pragma unroll
        for (int nq = 0; nq < 2; nq++) {
            #pragma unroll
            for (int hf = 0; hf < 2; hf++) {
                if ((c0 >> 3) == hf) {
                    int rho = c0 & 7;
                    #pragma unroll
                    for (int mk = 0; mk < 8; mk++) {
                        int k4 = mk * 4 + g;
                        ((floatx4*)myP)[rho * 32 + (k4 ^ rho)] = sacc[mk][nq];
                    }
                }
                const ll grow = (ll)bh * 2048 + qt * 128 + wave * 32 + nq * 16 + hf * 8;
                #pragma unroll
                for (int t = 0; t < 4; t++) {
                    int rr = t * 2 + (lane >> 5);
                    int k4r = lane & 31;
                    floatx4 v = ((const floatx4*)myP)[rr * 32 + (k4r ^ rr)];
                    __builtin_nontemporal_store(
                        v, (floatx4*)(atn + (grow + rr) * 2048 + kb * 128 + k4r * 4));
                }
            }
        }
        __syncthreads();
    }
}

// ---------------------------------------------------------------------------
// Attention pass 1, 8-wave blocks: per (bh, 256-row q pair). 8 waves share
// one K/V double-buffer (2 waves/SIMD; staging issue per wave halved;
// counted vmcnt(4)). No-max 2^x softmax (pre-scaled Q), x16-MFMA PV.
// sh 64KB: Kbuf0|Kbuf1|Vbuf0|Vbuf1 (16KB each); Q staged in first 32KB.
// ---------------------------------------------------------------------------
__global__ __launch_bounds__(512) void attn8_k(
    const unsigned short* __restrict__ qkv, const unsigned short* __restrict__ vt,
    unsigned short* __restrict__ attnb, float* __restrict__ ilbuf)
{
    __shared__ unsigned short sh[32768];

    const int tid = threadIdx.x, lane = tid & 63, w = tid >> 6;
    const int c0 = lane & 15, g = lane >> 4;
    const int srow = lane >> 3;
    const int ssw  = (((lane & 7) ^ srow)) << 3;
    const int kswz = (lane & 7) << 3;

    // XCD pinning: xcd = n&7 owns bh {xcd*4 .. xcd*4+3}
    const int n = blockIdx.x;                 // 0..255
    const int j = n >> 3;
    const int bh = (n & 7) * 4 + (j & 3);
    const int qp = j >> 2;                    // 0..7 (256-row pair)
    const int b = bh >> 3, h = bh & 7;

    const ll qbase  = ((ll)(b * 2048 + qp * 256)) * 1536 + h * 64;
    const ll kbase0 = ((ll)(b * 2048)) * 1536 + 512 + h * 64;
    const unsigned short* vbase = vt + (ll)bh * 64 * 2048;

    // stage Q [256][64] into sh[0..16384) (swizzled), pull B-fragments
    #pragma unroll
    for (int ii = 0; ii < 4; ++ii) {
        int i = w + ii * 8;
        gload16(qkv + qbase + (ll)(i * 8 + srow) * 1536 + ssw, sh + i * 512);
    }
    __syncthreads();
    short8 qf[2][2];
    #pragma unroll
    for (int nq = 0; nq < 2; nq++)
        #pragma unroll
        for (int kk = 0; kk < 2; kk++)
            qf[nq][kk] = *(const short8*)&sh[(w * 32 + nq * 16 + c0) * 64 + ((kk * 32 + g * 8) ^ kswz)];
    __syncthreads();

    floatx4 oaccT[4][2] = {};
    float l_run[2] = {0.f, 0.f};

#define STAGE_KV(kbx, bb) do {                                                   \
    const ll koff_ = kbase0 + (ll)(kbx) * 128 * 1536;                            \
    unsigned short* Kd_ = sh + ((bb) << 13);                                     \
    unsigned short* Vd_ = sh + 16384 + ((bb) << 13);                             \
    _Pragma("unroll")                                                            \
    for (int ii = 0; ii < 2; ++ii) { int i = w + ii * 8;                         \
        gload16(qkv + koff_ + (ll)(i * 8 + srow) * 1536 + ssw, Kd_ + i * 512); } \
    _Pragma("unroll")                                                            \
    for (int ii = 0; ii < 2; ++ii) { int i = w + ii * 8; int s = i * 8 + srow;   \
        int vrow = s >> 1; int vslot = ((s & 1) << 3) | (lane & 7);              \
        gload16(vbase + (ll)vrow * 2048 + (kbx) * 128 + ((vslot ^ (vrow & 7)) << 3), \
                Vd_ + i * 512); }                                                \
} while (0)

    STAGE_KV(0, 0);
    for (int kb = 0; kb < 16; ++kb) {
        const int cur = kb & 1;
        if (kb < 15) {
            STAGE_KV(kb + 1, cur ^ 1);
            asm volatile("s_waitcnt vmcnt(4)" ::: "memory");
        } else {
            asm volatile("s_waitcnt vmcnt(0)" ::: "memory");
        }
        __builtin_amdgcn_sched_barrier(0);
        __builtin_amdgcn_s_barrier();
        __builtin_amdgcn_sched_barrier(0);

        unsigned short* Kc = sh + (cur << 13);
        unsigned short* Vc = sh + 16384 + (cur << 13);

        // S^T = mfma(K, Q); Q pre-scaled so sacc is s*0.125*log2e
        floatx4 sacc[8][2] = {};
        #pragma unroll
        for (int kk = 0; kk < 2; kk++)
            #pragma unroll
            for (int mk = 0; mk < 8; mk++) {
                short8 kf = *(const short8*)&Kc[(mk * 16 + c0) * 64 + ((kk * 32 + g * 8) ^ kswz)];
                #pragma unroll
                for (int nq = 0; nq < 2; nq++)
                    sacc[mk][nq] = __builtin_amdgcn_mfma_f32_16x16x32_bf16(kf, qf[nq][kk], sacc[mk][nq], 0, 0, 0);
            }

        // p = 2^t; l += row-sum
        #pragma unroll
        for (int nq = 0; nq < 2; nq++) {
            float rs = 0.f;
            #pragma unroll
            for (int mk = 0; mk < 8; mk++)
                #pragma unroll
                for (int r = 0; r < 4; r++) {
                    float p = fexp2(sacc[mk][nq][r]);
                    sacc[mk][nq][r] = p;
                    rs += p;
                }
            rs += __shfl_xor(rs, 16);
            rs += __shfl_xor(rs, 32);
            l_run[nq] += rs;
        }

        // PV via x16 MFMA: P is already in B-fragment layout (k = g*4+r)
        #pragma unroll
        for (int mk = 0; mk < 8; mk++) {
            short4v pb[2];
            #pragma unroll
            for (int nq = 0; nq < 2; nq++) {
                union { unsigned int u[2]; short4v s; } pu;
                pu.u[0] = cvtpk(sacc[mk][nq][0], sacc[mk][nq][1]);
                pu.u[1] = cvtpk(sacc[mk][nq][2], sacc[mk][nq][3]);
                pb[nq] = pu.s;
            }
            #pragma unroll
            for (int mk2 = 0; mk2 < 4; mk2++) {
                short4v vf = *(const short4v*)&Vc[(mk2 * 16 + c0) * 128 + ((mk * 16 + g * 4) ^ kswz)];
                #pragma unroll
                for (int nq = 0; nq < 2; nq++)
                    oaccT[mk2][nq] = mfma16(vf, pb[nq], oaccT[mk2][nq]);
            }
        }
        __builtin_amdgcn_sched_barrier(0);
        __builtin_amdgcn_s_barrier();
        __builtin_amdgcn_sched_barrier(0);
    }
#undef STAGE_KV

    const float il[2] = { 1.0f / l_run[0], 1.0f / l_run[1] };

    #pragma unroll
    for (int nq = 0; nq < 2; nq++) {
        int qrow = qp * 256 + w * 32 + nq * 16 + c0;
        ll row = (ll)b * 2048 + qrow;
        #pragma unroll
        for (int mk2 = 0; mk2 < 4; mk2++) {
            int col = h * 64 + mk2 * 16 + g * 4;
            unsigned int r0 = cvtpk(oaccT[mk2][nq][0] * il[nq], oaccT[mk2][nq][1] * il[nq]);
            unsigned int r1 = cvtpk(oaccT[mk2][nq][2] * il[nq], oaccT[mk2][nq][3] * il[nq]);
            int2 tb = { (int)r0, (int)r1 };
            *(int2*)&attnb[row * 512 + col] = tb;
        }
        if (g == 0) ilbuf[(ll)bh * 2048 + qrow] = il[nq];
    }
}

// ---------------------------------------------------------------------------
// Fused GEMM+writers: writer blocks [0, WRCNT*16) for bh WRBH0..WRBH0+WRCNT-1,
// then GX*GY GEMM blocks (XCD-swizzled).
// ---------------------------------------------------------------------------
template<int WRBH0, int WRCNT, int GX, int GY, int BM, int BN, int EPI>
__global__ __launch_bounds__(TPB) void fusedg_k(
    const unsigned short* __restrict__ qkv, const float* __restrict__ ilbuf,
    float* __restrict__ atn,
    const unsigned short* __restrict__ Ap, const unsigned short* __restrict__ BTp,
    const float* __restrict__ bias, void* __restrict__ Cp,
    const unsigned short* __restrict__ Rb,
    int K, ll lda, ll ldb, ll ldc)
{
    __shared__ unsigned short sh[16384];
    const int bid = blockIdx.x;
    constexpr int WRN = WRCNT * 16;
    if (bid < WRN) {
        atnwrite_body(qkv, ilbuf, atn, WRBH0 + bid % WRCNT, bid / WRCNT, sh);
    } else {
        int sid = bid - WRN;
        constexpr int NWG = GX * GY;
        int w = (sid & 7) * (NWG >> 3) + (sid >> 3);
        int bx = w % GX, by = w / GX;
        gemm_body<BM, BN, EPI>(Ap, BTp, bias, Cp, Rb, nullptr, K, lda, ldb, ldc,
                               bx, by, sh, sh + BM * 64);
    }
}

// ---------------------------------------------------------------------------
// LayerNorm over rows of 512 bf16 -> f32 out (wave per row, 4 rows/block)
// ---------------------------------------------------------------------------
__global__ __launch_bounds__(TPB) void ln_k(const unsigned short* __restrict__ y,
                                            const float* __restrict__ gamma,
                                            const float* __restrict__ beta,
                                            float* __restrict__ out)
{
    const int lane = threadIdx.x & 63;
    const ll row = (ll)blockIdx.x * 4 + (threadIdx.x >> 6);
    short8 v = *(const short8*)(y + row * 512 + lane * 8);
    float f[8];
    float s = 0.f, q = 0.f;
    #pragma unroll
    for (int j = 0; j < 8; j++) {
        f[j] = bu2f((unsigned short)v[j]);
        s += f[j]; q += f[j] * f[j];
    }
    #pragma unroll
    for (int off = 32; off; off >>= 1) { s += __shfl_xor(s, off); q += __shfl_xor(q, off); }
    const float mu  = s * (1.0f / 512.0f);
    const float var = q * (1.0f / 512.0f) - mu * mu;
    const float rs  = rsqrtf(var + 1e-5f);

    float4 g0 = *(const float4*)(gamma + lane * 8);
    float4 g1 = *(const float4*)(gamma + lane * 8 + 4);
    float4 e0 = *(const float4*)(beta  + lane * 8);
    float4 e1 = *(const float4*)(beta  + lane * 8 + 4);
    floatx4 o0, o1;
    o0[0] = (f[0] - mu) * rs * g0.x + e0.x;  o0[1] = (f[1] - mu) * rs * g0.y + e0.y;
    o0[2] = (f[2] - mu) * rs * g0.z + e0.z;  o0[3] = (f[3] - mu) * rs * g0.w + e0.w;
    o1[0] = (f[4] - mu) * rs * g1.x + e1.x;  o1[1] = (f[5] - mu) * rs * g1.y + e1.y;
    o1[2] = (f[6] - mu) * rs * g1.z + e1.z;  o1[3] = (f[7] - mu) * rs * g1.w + e1.w;
    __builtin_nontemporal_store(o0, (floatx4*)(out + row * 512 + lane * 8));
    __builtin_nontemporal_store(o1, (floatx4*)(out + row * 512 + lane * 8 + 4));
}

// ---------------------------------------------------------------------------
// Prep: weight transposes (32x32 tiles) + bias concat + x cast, block-ranged.
// ---------------------------------------------------------------------------
__global__ __launch_bounds__(TPB) void prep_k(
    const float* __restrict__ Wq, const float* __restrict__ Wk,
    const float* __restrict__ Wv, const float* __restrict__ W1,
    const float* __restrict__ W2,
    const float* __restrict__ bq, const float* __restrict__ bk,
    const float* __restrict__ bv, const float* __restrict__ x,
    unsigned short* __restrict__ wtqkv, unsigned short* __restrict__ wt1,
    unsigned short* __restrict__ wt2, float* __restrict__ bqkv,
    unsigned short* __restrict__ xb)
{
    __shared__ float t[32 * 33];
    const int bid = blockIdx.x;
    const float* W; unsigned short* WT; int K, N, tile;
    if (bid < 256)       { W = Wq; WT = wtqkv;             K = 512;  N = 512;  tile = bid; }
    else if (bid < 512)  { W = Wk; WT = wtqkv + 512 * 512; K = 512;  N = 512;  tile = bid - 256; }
    else if (bid < 768)  { W = Wv; WT = wtqkv + 1024 * 512;K = 512;  N = 512;  tile = bid - 512; }
    else if (bid < 1792) { W = W1; WT = wt1;               K = 512;  N = 2048; tile = bid - 768; }
    else if (bid < 2816) { W = W2; WT = wt2;               K = 2048; N = 512;  tile = bid - 1792; }
    else if (bid < 2822) {
        int i = (bid - 2816) * TPB + threadIdx.x;
        if (i < 512)       bqkv[i] = bq[i];
        else if (i < 1024) bqkv[i] = bk[i - 512];
        else if (i < 1536) bqkv[i] = bv[i - 1024];
        return;
    } else {
        ll i = ((ll)(bid - 2822) * TPB + threadIdx.x) * 4;
        float4 v = *(const float4*)(x + i);
        unsigned int r0 = cvtpk(v.x, v.y), r1 = cvtpk(v.z, v.w);
        int2 tt = { (int)r0, (int)r1 };
        *(int2*)(xb + i) = tt;
        return;
    }
    const int nx = N >> 5;
    const int n0 = (tile % nx) * 32, k0 = (tile / nx) * 32;
    const int tx = threadIdx.x & 31, ty = threadIdx.x >> 5;
    #pragma unroll
    for (int i = ty; i < 32; i += 8) t[i * 33 + tx] = W[(ll)(k0 + i) * N + n0 + tx];
    __syncthreads();
    #pragma unroll
    for (int i = ty; i < 32; i += 8) WT[(ll)(n0 + i) * K + k0 + tx] = f2bu(t[tx * 33 + i]);
}

// ---------------------------------------------------------------------------
extern "C" void kernel_launch(void* const* d_in, const int* in_sizes, int n_in,
                              void* d_out, int out_size, void* d_ws, size_t ws_size,
                              hipStream_t stream)
{
    (void)in_sizes; (void)n_in; (void)out_size; (void)ws_size;
    const float* x     = (const float*)d_in[0];
    const float* Wq    = (const float*)d_in[1];
    const float* bq    = (const float*)d_in[2];
    const float* Wk    = (const float*)d_in[3];
    const float* bk    = (const float*)d_in[4];
    const float* Wv    = (const float*)d_in[5];
    const float* bv    = (const float*)d_in[6];
    const float* W1    = (const float*)d_in[7];
    const float* b1    = (const float*)d_in[8];
    const float* W2    = (const float*)d_in[9];
    const float* b2    = (const float*)d_in[10];
    const float* gamma = (const float*)d_in[11];
    const float* beta  = (const float*)d_in[12];

    char* ws = (char*)d_ws;
    size_t off = 0;
    auto alloc = [&](size_t bytes) -> char* {
        char* p = ws + off; off += (bytes + 255) & ~(size_t)255; return p;
    };
    unsigned short* xb    = (unsigned short*)alloc(8192ll * 512 * 2);
    unsigned short* wtqkv = (unsigned short*)alloc(1536ll * 512 * 2);
    unsigned short* wt1   = (unsigned short*)alloc(2048ll * 512 * 2);
    unsigned short* wt2   = (unsigned short*)alloc(512ll * 2048 * 2);
    float*          bqkv  = (float*)alloc(1536 * 4);
    unsigned short* qkv   = (unsigned short*)alloc(8192ll * 1536 * 2);
    unsigned short* vt    = (unsigned short*)alloc(32ll * 64 * 2048 * 2);
    unsigned short* attnb = (unsigned short*)alloc(8192ll * 512 * 2);
    unsigned short* hmid  = (unsigned short*)alloc(8192ll * 2048 * 2);
    unsigned short* ybuf  = (unsigned short*)alloc(8192ll * 512 * 2);
    float*          ilbuf = (float*)alloc(32ll * 2048 * 4);

    float* outp = (float*)d_out;
    float* atn  = outp + 4194304;     // [B,H,S,S] region

    prep_k<<<2822 + 4096, TPB, 0, stream>>>(Wq, Wk, Wv, W1, W2, bq, bk, bv, x,
                                            wtqkv, wt1, wt2, bqkv, xb);

    // QKV: [8192,512] @ [512,1536]; Q cols pre-scaled; V written transposed to vt
    gemm_k<128, 128, 7><<<dim3(64, 12, 1), TPB, 0, stream>>>(
        xb, wtqkv, bqkv, qkv, nullptr, vt, 512, 512, 512, 1536);

    // Attention (all 32 bh): attn_out (bf16) + per-row 1/l; 8-wave blocks
    attn8_k<<<256, 512, 0, stream>>>(qkv, vt, attnb, ilbuf);

    // Fused 2: writers bh 0..15 || FFN1 relu(attn_out@W1+b1) -> hmid
    fusedg_k<0, 16, 64, 16, 128, 128, 3><<<256 + 1024, TPB, 0, stream>>>(
        qkv, ilbuf, atn,
        attnb, wt1, b1, hmid, nullptr, 512, 512, 512, 2048);

    // Fused 3: writers bh 16..31 || FFN2 hmid@W2+b2+attn_out(bf16) -> ybuf bf16
    fusedg_k<16, 16, 128, 4, 64, 128, 6><<<256 + 512, TPB, 0, stream>>>(
        qkv, ilbuf, atn,
        hmid, wt2, b2, ybuf, attnb, 2048, 2048, 2048, 512);

    ln_k<<<2048, TPB, 0, stream>>>(ybuf, gamma, beta, outp);
}